// Round 9
// baseline (675.745 us; speedup 1.0000x reference)
//
#include <hip/hip_runtime.h>
#include <hip/hip_fp16.h>
#include <math.h>

#define HID 128
#define NCLS 32
#define BCAP 12288   // per-bucket capacity in bins (mean 8704, +38 sigma)
#define SCAP 9728    // LDS sort capacity (mean 8704, +11 sigma)
#define NSLICE 13    // src slices of 8192 nodes (src>>13, N=100K -> 0..12)
#define NBINS 7168   // 13*512 padded to 1024*7

typedef _Float16 half8 __attribute__((ext_vector_type(8)));
typedef _Float16 h2 __attribute__((ext_vector_type(2)));
typedef float f32x4 __attribute__((ext_vector_type(4)));

__device__ __forceinline__ void gload_lds16(const void* g, void* l) {
  __builtin_amdgcn_global_load_lds(
      (const __attribute__((address_space(1))) void*)g,
      (__attribute__((address_space(3))) void*)l, 16, 0, 0);
}

// monotone fp32 <-> uint mapping so unsigned max == float max
__device__ __forceinline__ unsigned flip32(float f) {
  int b = __float_as_int(f);
  return (unsigned)(b ^ ((b >> 31) | 0x80000000));
}
__device__ __forceinline__ float unflip32(unsigned u) {
  unsigned mask = ((int)u < 0) ? 0x80000000u : 0xFFFFFFFFu;
  return __int_as_float((int)(u ^ mask));
}

// ---------------------------------------------------------------- prep
__global__ void k_prep_x(const float* __restrict__ x, __half* __restrict__ xa,
                         int total4) {
  int i = blockIdx.x * blockDim.x + threadIdx.x;
  if (i >= total4) return;
  float4 v = ((const float4*)x)[i];
  __half2* o = (__half2*)xa + i * 2;
  o[0] = __floats2half2_rn(v.x, v.y);
  o[1] = __floats2half2_rn(v.z, v.w);
}

__global__ void k_prep_w(const float* __restrict__ Ws, __half* __restrict__ Wt,
                         int total) {
  int i = blockIdx.x * blockDim.x + threadIdx.x;
  if (i >= total) return;
  int l = i >> 14, r = i & 16383;
  int nn = r >> 7, k = r & 127;
  Wt[i] = __float2half_rn(Ws[(l << 14) + k * HID + nn]);
}

// ---------------------------------------------------------------- binned CSR build
__global__ __launch_bounds__(1024) void k_bin(const int* __restrict__ ei,
                                              const float* __restrict__ norm,
                                              int* __restrict__ bucket_cur,
                                              int2* __restrict__ bins,
                                              int E, int T) {
  __shared__ int bcnt[256];
  __shared__ int bbase[256];
  int tid = threadIdx.x;
  if (tid < 256) bcnt[tid] = 0;
  __syncthreads();
  int base = blockIdx.x * 8192;
  int2 ent[8];
  int bk[8];
  #pragma unroll
  for (int i = 0; i < 8; ++i) {
    int e = base + (i << 10) + tid;
    bk[i] = -1;
    if (e < T) {
      int src, dst;
      if (e < E) { src = ei[e]; dst = ei[E + e]; } else { src = dst = e - E; }
      bk[i] = dst >> 9;
      ent[i] = make_int2(src | ((dst & 511) << 17), __float_as_int(norm[e]));
      atomicAdd(&bcnt[bk[i]], 1);
    }
  }
  __syncthreads();
  if (tid < 256) {
    int c = bcnt[tid];
    bbase[tid] = c ? atomicAdd(&bucket_cur[tid], c) : 0;
    bcnt[tid] = 0;
  }
  __syncthreads();
  #pragma unroll
  for (int i = 0; i < 8; ++i) {
    if (bk[i] >= 0) {
      int pos = bbase[bk[i]] + atomicAdd(&bcnt[bk[i]], 1);
      bins[(size_t)bk[i] * BCAP + pos] = ent[i];
    }
  }
}

__global__ __launch_bounds__(256) void k_bscan(const int* __restrict__ bucket_cur,
                                               int* __restrict__ bucket_off, int nb) {
  __shared__ int a[256];
  int tid = threadIdx.x;
  int orig = (tid < nb) ? bucket_cur[tid] : 0;
  a[tid] = orig;
  __syncthreads();
  for (int d = 1; d < 256; d <<= 1) {
    int t = (tid >= d) ? a[tid - d] : 0;
    __syncthreads();
    a[tid] += t;
    __syncthreads();
  }
  if (tid < nb) bucket_off[tid] = a[tid] - orig;
  if (tid == nb - 1) bucket_off[nb] = a[tid];
}

// sort bucket edges by (src-slice, dstLocal): slice-major for L2 sweep locality.
__global__ __launch_bounds__(1024) void k_sortbucket(
    const int2* __restrict__ bins, const int* __restrict__ bucket_off,
    int2* __restrict__ csr, int n, int nb) {
  __shared__ int2 sorted[SCAP];
  __shared__ int cnt_[NBINS];
  __shared__ int wsum[16];
  int b = blockIdx.x, tid = threadIdx.x;
  int goff = bucket_off[b];
  int cnt = bucket_off[b + 1] - goff;
  if (cnt > SCAP) cnt = SCAP;
  const int2* src = bins + (size_t)b * BCAP;
  int2 myent[10];
  int mykey[10];
  #pragma unroll
  for (int i = 0; i < 10; ++i) {
    int j = tid + (i << 10);
    if (j < cnt) {
      myent[i] = src[j];
      int s = (myent[i].x & 0x1FFFF) >> 13;            // slice
      int dl = ((unsigned)myent[i].x) >> 17;           // dstLocal
      mykey[i] = (s << 9) + dl;
    }
  }
  #pragma unroll
  for (int i = 0; i < 7; ++i) cnt_[tid + (i << 10)] = 0;
  __syncthreads();
  #pragma unroll
  for (int i = 0; i < 10; ++i) {
    int j = tid + (i << 10);
    if (j < cnt) atomicAdd(&cnt_[mykey[i]], 1);
  }
  __syncthreads();
  // exclusive scan of cnt_[7168]: 7 bins per thread, then block scan
  int base = tid * 7;
  int loc[7];
  int s0 = 0;
  #pragma unroll
  for (int k = 0; k < 7; ++k) { loc[k] = s0; s0 += cnt_[base + k]; }
  int lane = tid & 63, wid = tid >> 6;
  int incl = s0;
  #pragma unroll
  for (int d = 1; d < 64; d <<= 1) {
    int t = __shfl_up(incl, d, 64);
    if (lane >= d) incl += t;
  }
  if (lane == 63) wsum[wid] = incl;
  __syncthreads();
  if (wid == 0 && lane < 16) {
    int wv = wsum[lane];
    int winc = wv;
    #pragma unroll
    for (int d = 1; d < 16; d <<= 1) {
      int t = __shfl_up(winc, d, 16);
      if (lane >= d) winc += t;
    }
    wsum[lane] = winc - wv;
  }
  __syncthreads();
  int excl = incl - s0 + wsum[wid];
  #pragma unroll
  for (int k = 0; k < 7; ++k) cnt_[base + k] = excl + loc[k];
  __syncthreads();
  #pragma unroll
  for (int i = 0; i < 10; ++i) {
    int j = tid + (i << 10);
    if (j < cnt) {
      int pos = atomicAdd(&cnt_[mykey[i]], 1);
      if (pos < SCAP) sorted[pos] = myent[i];   // keep src|dl<<17 intact
    }
  }
  __syncthreads();
  for (int j = tid; j < cnt; j += 1024) csr[goff + j] = sorted[j];
}

// ---------------------------------------------------------------- MFMA GEMM (r7 64-row config)
__global__ __launch_bounds__(256) void k_gemm_mfma(const __half* __restrict__ X,
                                                   const __half* __restrict__ Wl,
                                                   __half* __restrict__ H, int n) {
  __shared__ char lds[49152];
  char* ldsW = lds;
  char* ldsX = lds + 32768;
  int tid = threadIdx.x, lane = tid & 63, w = tid >> 6;
  int row0 = blockIdx.x * 64;
  int rows = n - row0; if (rows > 64) rows = 64;
  int vbytes = rows << 8;

  #pragma unroll
  for (int it = 0; it < 8; ++it) {
    int d = (w << 13) + (it << 10) + (lane << 4);
    int src = d ^ (((d >> 8) & 7) << 4);
    gload_lds16((const char*)Wl + src, ldsW + (w << 13) + (it << 10));
  }
  #pragma unroll
  for (int it = 0; it < 4; ++it) {
    int d = (w << 12) + (it << 10) + (lane << 4);
    if (d < vbytes) {
      int src = d ^ (((d >> 8) & 7) << 4);
      gload_lds16((const char*)X + ((size_t)row0 << 8) + src,
                  ldsX + (w << 12) + (it << 10));
    }
  }
  __syncthreads();

  int l15 = lane & 15, lhi = lane >> 4;
  half8 a[4];
  #pragma unroll
  for (int s = 0; s < 4; ++s) {
    int m = (w << 4) + l15;
    int d = (m << 8) + (s << 6) + (lhi << 4);
    a[s] = *(const half8*)(ldsX + (d ^ ((m & 7) << 4)));
  }
  f32x4 acc[8] = {};
  #pragma unroll
  for (int s = 0; s < 4; ++s) {
    #pragma unroll
    for (int t = 0; t < 8; ++t) {
      int nn = (t << 4) + l15;
      int d = (nn << 8) + (s << 6) + (lhi << 4);
      half8 b = *(const half8*)(ldsW + (d ^ ((nn & 7) << 4)));
      acc[t] = __builtin_amdgcn_mfma_f32_16x16x32_f16(a[s], b, acc[t], 0, 0, 0);
    }
  }
  #pragma unroll
  for (int t = 0; t < 8; ++t) {
    int col = (t << 4) + l15;
    #pragma unroll
    for (int r = 0; r < 4; ++r) {
      int row = row0 + (w << 4) + (lhi << 2) + r;
      if (row < n) H[(size_t)row * HID + col] = __float2half_rn(acc[t][r]);
    }
  }
}

// ---------------------------------------------------------------- aggregate v3
// 4 blocks per bucket, each owns a 64B channel-stripe; block scans the bucket's
// slice-major edge list; LDS fp32 flipped-int atomicMax accumulators [ch][node];
// no barriers (each wave owns its 8-channel rows end-to-end).
// blockIdx mapping ties stripe to XCD pairs: i=g*8+xcd -> c=xcd>>1, b=g*2+(xcd&1).
__global__ __launch_bounds__(256) void k_aggregate(
    const __half* __restrict__ H, const int* __restrict__ bucket_off,
    const int2* __restrict__ csr, const float* __restrict__ bias,
    __half* __restrict__ Xout, int n) {
  __shared__ unsigned acc[32][512];   // 64 KB, ch-major: bank = node
  int i = blockIdx.x;
  int c = (i & 7) >> 1;               // channel-stripe 0..3
  int b = ((i >> 3) << 1) + (i & 1);  // bucket 0..nb-1
  int tid = threadIdx.x, wv = tid >> 6, lane = tid & 63;

  {  // init my wave's 8 rows to flipped(-inf)
    unsigned* p = &acc[wv << 3][0];
    #pragma unroll
    for (int k = 0; k < 64; ++k) p[(k << 6) + lane] = 0x007FFFFFu;
  }
  int goff = bucket_off[b];
  int cnt = bucket_off[b + 1] - goff;
  const char* Hb = (const char*)H + (c << 6) + (wv << 4);

  for (int j0 = 0; j0 < cnt; j0 += 128) {
    int ja = j0 + lane, jb = j0 + 64 + lane;
    bool va = ja < cnt, vb = jb < cnt;
    int2 ea, eb;
    uint4 ra, rb;
    if (va) ea = csr[goff + ja];
    if (vb) eb = csr[goff + jb];
    if (va) ra = *(const uint4*)(Hb + ((size_t)(ea.x & 0x1FFFF) << 8));
    if (vb) rb = *(const uint4*)(Hb + ((size_t)(eb.x & 0x1FFFF) << 8));
    if (va) {
      int dl = ((unsigned)ea.x) >> 17;
      _Float16 w = (_Float16)__int_as_float(ea.y);
      h2 p0 = *(h2*)&ra.x * w, p1 = *(h2*)&ra.y * w;
      h2 p2 = *(h2*)&ra.z * w, p3 = *(h2*)&ra.w * w;
      unsigned* row = &acc[wv << 3][dl];
      atomicMax(row,          flip32((float)p0.x));
      atomicMax(row + 512,    flip32((float)p0.y));
      atomicMax(row + 1024,   flip32((float)p1.x));
      atomicMax(row + 1536,   flip32((float)p1.y));
      atomicMax(row + 2048,   flip32((float)p2.x));
      atomicMax(row + 2560,   flip32((float)p2.y));
      atomicMax(row + 3072,   flip32((float)p3.x));
      atomicMax(row + 3584,   flip32((float)p3.y));
    }
    if (vb) {
      int dl = ((unsigned)eb.x) >> 17;
      _Float16 w = (_Float16)__int_as_float(eb.y);
      h2 p0 = *(h2*)&rb.x * w, p1 = *(h2*)&rb.y * w;
      h2 p2 = *(h2*)&rb.z * w, p3 = *(h2*)&rb.w * w;
      unsigned* row = &acc[wv << 3][dl];
      atomicMax(row,          flip32((float)p0.x));
      atomicMax(row + 512,    flip32((float)p0.y));
      atomicMax(row + 1024,   flip32((float)p1.x));
      atomicMax(row + 1536,   flip32((float)p1.y));
      atomicMax(row + 2048,   flip32((float)p2.x));
      atomicMax(row + 2560,   flip32((float)p2.y));
      atomicMax(row + 3072,   flip32((float)p3.x));
      atomicMax(row + 3584,   flip32((float)p3.y));
    }
  }
  // output my wave's 8 channels for all nodes of the bucket (no barrier needed)
  int chb = (c << 5) + (wv << 3);
  float4 b0 = *(const float4*)&bias[chb];
  float4 b1 = *(const float4*)&bias[chb + 4];
  int nodebase = b << 9;
  #pragma unroll
  for (int it = 0; it < 8; ++it) {
    int dl = (it << 6) + lane;
    int node = nodebase + dl;
    if (node < n) {
      unsigned* row = &acc[wv << 3][dl];
      float v0 = unflip32(row[0])    + b0.x;
      float v1 = unflip32(row[512])  + b0.y;
      float v2 = unflip32(row[1024]) + b0.z;
      float v3 = unflip32(row[1536]) + b0.w;
      float v4 = unflip32(row[2048]) + b1.x;
      float v5 = unflip32(row[2560]) + b1.y;
      float v6 = unflip32(row[3072]) + b1.z;
      float v7 = unflip32(row[3584]) + b1.w;
      __half2 o0 = __floats2half2_rn(fmaxf(v0, 0.f), fmaxf(v1, 0.f));
      __half2 o1 = __floats2half2_rn(fmaxf(v2, 0.f), fmaxf(v3, 0.f));
      __half2 o2 = __floats2half2_rn(fmaxf(v4, 0.f), fmaxf(v5, 0.f));
      __half2 o3 = __floats2half2_rn(fmaxf(v6, 0.f), fmaxf(v7, 0.f));
      uint4 ov = make_uint4(*(unsigned*)&o0, *(unsigned*)&o1,
                            *(unsigned*)&o2, *(unsigned*)&o3);
      *(uint4*)((char*)Xout + ((size_t)node << 8) + (c << 6) + (wv << 4)) = ov;
    }
  }
}

// ---------------------------------------------------------------- classifier + log_softmax
__global__ __launch_bounds__(256) void k_classifier(
    const __half* __restrict__ X, const float* __restrict__ Wc,
    const float* __restrict__ bc, float* __restrict__ out, int n) {
  __shared__ float sW[HID * NCLS];
  __shared__ float sx[8][HID];
  int tid = threadIdx.x;
  #pragma unroll
  for (int i = 0; i < 4; ++i)
    ((float4*)sW)[tid + 256 * i] = ((const float4*)Wc)[tid + 256 * i];
  int node0 = blockIdx.x * 8;
  {
    int r = tid >> 5, c = (tid & 31) << 2;
    if (node0 + r < n) {
      __half2 p0 = *(const __half2*)&X[(size_t)(node0 + r) * HID + c];
      __half2 p1 = *(const __half2*)&X[(size_t)(node0 + r) * HID + c + 2];
      float2 f0 = __half22float2(p0), f1 = __half22float2(p1);
      sx[r][c] = f0.x; sx[r][c + 1] = f0.y; sx[r][c + 2] = f1.x; sx[r][c + 3] = f1.y;
    }
  }
  __syncthreads();
  int g = tid >> 5, c = tid & 31;
  int node = node0 + g;
  if (node >= n) return;
  float acc = bc[c];
  #pragma unroll 8
  for (int k = 0; k < HID; ++k)
    acc = fmaf(sx[g][k], sW[k * NCLS + c], acc);
  float m = acc;
  #pragma unroll
  for (int off = 16; off; off >>= 1) m = fmaxf(m, __shfl_xor(m, off, 32));
  float e = expf(acc - m);
  float s = e;
  #pragma unroll
  for (int off = 16; off; off >>= 1) s += __shfl_xor(s, off, 32);
  out[(size_t)node * NCLS + c] = acc - m - logf(s);
}

// ---------------------------------------------------------------- launch
extern "C" void kernel_launch(void* const* d_in, const int* in_sizes, int n_in,
                              void* d_out, int out_size, void* d_ws, size_t ws_size,
                              hipStream_t stream) {
  const float* x    = (const float*)d_in[0];
  const int*   ei   = (const int*)d_in[1];
  const float* norm = (const float*)d_in[2];
  const float* Ws   = (const float*)d_in[3];
  const float* bs   = (const float*)d_in[4];
  const float* Wc   = (const float*)d_in[5];
  const float* bc   = (const float*)d_in[6];
  float* out = (float*)d_out;

  const int N = in_sizes[0] / HID;
  const int E = in_sizes[1] / 2;
  const int L = in_sizes[3] / (HID * HID);
  const int T = E + N;
  const int NB = (N + 511) >> 9;

  char* p = (char*)d_ws;
  auto alloc = [&](size_t bytes) {
    char* r = p; p += (bytes + 255) & ~(size_t)255; return r;
  };
  __half* xa         = (__half*)alloc((size_t)N * HID * 2);
  __half* xb         = (__half*)alloc((size_t)N * HID * 2);
  __half* hbuf       = (__half*)alloc((size_t)N * HID * 2);
  __half* Wt         = (__half*)alloc((size_t)L * HID * HID * 2);
  int*    bucket_cur = (int*)alloc(256 * 4);
  int*    bucket_off = (int*)alloc(257 * 4);
  int2*   bins       = (int2*)alloc((size_t)NB * BCAP * 8);
  int2*   csr        = (int2*)alloc((size_t)T * 8);
  (void)ws_size; (void)n_in; (void)out_size;

  hipMemsetAsync(bucket_cur, 0, 256 * 4, stream);
  k_prep_x<<<(N * 32 + 255) / 256, 256, 0, stream>>>(x, xa, N * 32);
  k_prep_w<<<(L * HID * HID + 255) / 256, 256, 0, stream>>>(Ws, Wt, L * HID * HID);
  k_bin<<<(T + 8191) / 8192, 1024, 0, stream>>>(ei, norm, bucket_cur, bins, E, T);
  k_bscan<<<1, 256, 0, stream>>>(bucket_cur, bucket_off, NB);
  k_sortbucket<<<NB, 1024, 0, stream>>>(bins, bucket_off, csr, N, NB);

  __half* xin = xa;
  __half* xout = xb;
  for (int l = 0; l < L; ++l) {
    k_gemm_mfma<<<(N + 63) / 64, 256, 0, stream>>>(
        xin, Wt + (size_t)l * HID * HID, hbuf, N);
    k_aggregate<<<((NB + 1) / 2) * 8, 256, 0, stream>>>(
        hbuf, bucket_off, csr, bs + (size_t)l * HID, xout, N);
    __half* tmp = xin; xin = xout; xout = tmp;
  }
  k_classifier<<<(N + 7) / 8, 256, 0, stream>>>(xin, Wc, bc, out, N);
}

// Round 10
// 626.221 us; speedup vs baseline: 1.0791x; 1.0791x over previous
//
#include <hip/hip_runtime.h>
#include <hip/hip_fp16.h>
#include <math.h>

#define HID 128
#define NCLS 32
#define BCAP 12288   // per-bucket capacity in bins (mean 8704, +38 sigma)
#define SCAP 9728    // LDS sort capacity (mean 8704, +11 sigma)

typedef _Float16 half8 __attribute__((ext_vector_type(8)));
typedef _Float16 h2 __attribute__((ext_vector_type(2)));
typedef float f32x4 __attribute__((ext_vector_type(4)));

union hbits_u { unsigned short u; _Float16 f; };

__device__ __forceinline__ void gload_lds16(const void* g, void* l) {
  __builtin_amdgcn_global_load_lds(
      (const __attribute__((address_space(1))) void*)g,
      (__attribute__((address_space(3))) void*)l, 16, 0, 0);
}

__device__ __forceinline__ h2 pk_max(h2 a, h2 b) {
  return __builtin_elementwise_max(a, b);   // v_pk_max_f16
}

__device__ __forceinline__ _Float16 dec_w(unsigned e) {
  hbits_u u; u.u = (unsigned short)((e >> 16) & 0xFFFEu);
  return u.f;
}

// ---------------------------------------------------------------- prep
__global__ void k_prep_x(const float* __restrict__ x, __half* __restrict__ xa,
                         int total4) {
  int i = blockIdx.x * blockDim.x + threadIdx.x;
  if (i >= total4) return;
  float4 v = ((const float4*)x)[i];
  __half2* o = (__half2*)xa + i * 2;
  o[0] = __floats2half2_rn(v.x, v.y);
  o[1] = __floats2half2_rn(v.z, v.w);
}

__global__ void k_prep_w(const float* __restrict__ Ws, __half* __restrict__ Wt,
                         int total) {
  int i = blockIdx.x * blockDim.x + threadIdx.x;
  if (i >= total) return;
  int l = i >> 14, r = i & 16383;
  int nn = r >> 7, k = r & 127;
  Wt[i] = __float2half_rn(Ws[(l << 14) + k * HID + nn]);
}

// ---------------------------------------------------------------- binned CSR build
__global__ __launch_bounds__(1024) void k_bin(const int* __restrict__ ei,
                                              const float* __restrict__ norm,
                                              int* __restrict__ bucket_cur,
                                              int2* __restrict__ bins,
                                              int E, int T) {
  __shared__ int bcnt[256];
  __shared__ int bbase[256];
  int tid = threadIdx.x;
  if (tid < 256) bcnt[tid] = 0;
  __syncthreads();
  int base = blockIdx.x * 8192;
  int2 ent[8];
  int bk[8];
  #pragma unroll
  for (int i = 0; i < 8; ++i) {
    int e = base + (i << 10) + tid;
    bk[i] = -1;
    if (e < T) {
      int src, dst;
      if (e < E) { src = ei[e]; dst = ei[E + e]; } else { src = dst = e - E; }
      bk[i] = dst >> 9;
      ent[i] = make_int2(src | ((dst & 511) << 17), __float_as_int(norm[e]));
      atomicAdd(&bcnt[bk[i]], 1);
    }
  }
  __syncthreads();
  if (tid < 256) {
    int c = bcnt[tid];
    bbase[tid] = c ? atomicAdd(&bucket_cur[tid], c) : 0;
    bcnt[tid] = 0;
  }
  __syncthreads();
  #pragma unroll
  for (int i = 0; i < 8; ++i) {
    if (bk[i] >= 0) {
      int pos = bbase[bk[i]] + atomicAdd(&bcnt[bk[i]], 1);
      bins[(size_t)bk[i] * BCAP + pos] = ent[i];
    }
  }
}

__global__ __launch_bounds__(256) void k_bscan(const int* __restrict__ bucket_cur,
                                               int* __restrict__ bucket_off, int nb) {
  __shared__ int a[256];
  int tid = threadIdx.x;
  int orig = (tid < nb) ? bucket_cur[tid] : 0;
  a[tid] = orig;
  __syncthreads();
  for (int d = 1; d < 256; d <<= 1) {
    int t = (tid >= d) ? a[tid - d] : 0;
    __syncthreads();
    a[tid] += t;
    __syncthreads();
  }
  if (tid < nb) bucket_off[tid] = a[tid] - orig;
  if (tid == nb - 1) bucket_off[nb] = a[tid];
}

// per-bucket counting sort by dstLocal; emits row_off + packed 4B csr entries
// (src:17 | norm-fp15:15).
__global__ __launch_bounds__(1024) void k_sortbucket(
    const int2* __restrict__ bins, const int* __restrict__ bucket_off,
    unsigned* __restrict__ csr4, int* __restrict__ row_off, int n, int nb) {
  __shared__ unsigned sorted[SCAP];
  __shared__ int scnt[512];
  __shared__ int wsum[8];
  int b = blockIdx.x, tid = threadIdx.x;
  int goff = bucket_off[b];
  int cnt = bucket_off[b + 1] - goff;
  if (cnt > SCAP) cnt = SCAP;
  const int2* src = bins + (size_t)b * BCAP;
  int2 myent[10];
  #pragma unroll
  for (int i = 0; i < 10; ++i) {
    int j = tid + (i << 10);
    if (j < cnt) myent[i] = src[j];
  }
  if (tid < 512) scnt[tid] = 0;
  __syncthreads();
  #pragma unroll
  for (int i = 0; i < 10; ++i) {
    int j = tid + (i << 10);
    if (j < cnt) atomicAdd(&scnt[((unsigned)myent[i].x) >> 17], 1);
  }
  __syncthreads();
  int lane = tid & 63, wid = tid >> 6;
  int v = (tid < 512) ? scnt[tid] : 0;
  int incl = v;
  #pragma unroll
  for (int d = 1; d < 64; d <<= 1) {
    int t = __shfl_up(incl, d, 64);
    if (lane >= d) incl += t;
  }
  if (tid < 512 && lane == 63) wsum[wid] = incl;
  __syncthreads();
  if (tid == 0) {
    int s = 0;
    #pragma unroll
    for (int i = 0; i < 8; ++i) { int t = wsum[i]; wsum[i] = s; s += t; }
  }
  __syncthreads();
  int excl = incl - v + ((tid < 512) ? wsum[wid] : 0);
  int node = (b << 9) + tid;
  if (tid < 512 && node < n) row_off[node] = goff + excl;
  if (b == nb - 1 && tid == 0) row_off[n] = bucket_off[nb];
  __syncthreads();
  if (tid < 512) scnt[tid] = excl;
  __syncthreads();
  #pragma unroll
  for (int i = 0; i < 10; ++i) {
    int j = tid + (i << 10);
    if (j < cnt) {
      int2 e = myent[i];
      int pos = atomicAdd(&scnt[((unsigned)e.x) >> 17], 1);
      if (pos < SCAP) {
        __half h = __float2half_rn(__int_as_float(e.y));
        unsigned short hb = *(unsigned short*)&h;
        sorted[pos] = (unsigned)(e.x & 0x1FFFF) | ((unsigned)(hb >> 1) << 17);
      }
    }
  }
  __syncthreads();
  for (int j = tid; j < cnt; j += 1024) csr4[goff + j] = sorted[j];
}

// ---------------------------------------------------------------- MFMA GEMM (64-row config)
__global__ __launch_bounds__(256) void k_gemm_mfma(const __half* __restrict__ X,
                                                   const __half* __restrict__ Wl,
                                                   __half* __restrict__ H, int n) {
  __shared__ char lds[49152];
  char* ldsW = lds;
  char* ldsX = lds + 32768;
  int tid = threadIdx.x, lane = tid & 63, w = tid >> 6;
  int row0 = blockIdx.x * 64;
  int rows = n - row0; if (rows > 64) rows = 64;
  int vbytes = rows << 8;

  #pragma unroll
  for (int it = 0; it < 8; ++it) {
    int d = (w << 13) + (it << 10) + (lane << 4);
    int src = d ^ (((d >> 8) & 7) << 4);
    gload_lds16((const char*)Wl + src, ldsW + (w << 13) + (it << 10));
  }
  #pragma unroll
  for (int it = 0; it < 4; ++it) {
    int d = (w << 12) + (it << 10) + (lane << 4);
    if (d < vbytes) {
      int src = d ^ (((d >> 8) & 7) << 4);
      gload_lds16((const char*)X + ((size_t)row0 << 8) + src,
                  ldsX + (w << 12) + (it << 10));
    }
  }
  __syncthreads();

  int l15 = lane & 15, lhi = lane >> 4;
  half8 a[4];
  #pragma unroll
  for (int s = 0; s < 4; ++s) {
    int m = (w << 4) + l15;
    int d = (m << 8) + (s << 6) + (lhi << 4);
    a[s] = *(const half8*)(ldsX + (d ^ ((m & 7) << 4)));
  }
  f32x4 acc[8] = {};
  #pragma unroll
  for (int s = 0; s < 4; ++s) {
    #pragma unroll
    for (int t = 0; t < 8; ++t) {
      int nn = (t << 4) + l15;
      int d = (nn << 8) + (s << 6) + (lhi << 4);
      half8 b = *(const half8*)(ldsW + (d ^ ((nn & 7) << 4)));
      acc[t] = __builtin_amdgcn_mfma_f32_16x16x32_f16(a[s], b, acc[t], 0, 0, 0);
    }
  }
  #pragma unroll
  for (int t = 0; t < 8; ++t) {
    int col = (t << 4) + l15;
    #pragma unroll
    for (int r = 0; r < 4; ++r) {
      int row = row0 + (w << 4) + (lhi << 2) + r;
      if (row < n) H[(size_t)row * HID + col] = __float2half_rn(acc[t][r]);
    }
  }
}

// ---------------------------------------------------------------- aggregate v4
// stripe-split gather: 4 blocks per node-group, block owns a 64B channel
// stripe; blockIdx maps stripe->XCD pair (c=(i&7)>>1) so per-XCD distinct
// H lines ~= H/4. Wave per node, quarter-wave per edge, lane loads 4B,
// 16 edges in flight, packed-fp16 math, shfl merge. No LDS, no atomics.
__global__ __launch_bounds__(256) void k_aggregate(
    const __half* __restrict__ H, const int* __restrict__ row_off,
    const unsigned* __restrict__ csr4, const float* __restrict__ bias,
    __half* __restrict__ Xout, int n) {
  int i = blockIdx.x;
  int c = (i & 7) >> 1;                    // stripe 0..3
  int g = ((i >> 3) << 1) + (i & 1);       // node-group
  int wv = threadIdx.x >> 6, lane = threadIdx.x & 63;
  int node = (g << 2) + wv;
  if (node >= n) return;
  int q = lane >> 4, l4 = lane & 15;
  int beg = row_off[node], end = row_off[node + 1];
  const char* Hb = (const char*)H + (c << 6) + (l4 << 2);
  const unsigned NEG = 0xFC00FC00u;
  h2 m = *(const h2*)&NEG;
  int j = beg + q;
  for (; j + 12 < end; j += 16) {
    unsigned e0 = csr4[j], e1 = csr4[j + 4], e2 = csr4[j + 8], e3 = csr4[j + 12];
    unsigned r0 = *(const unsigned*)(Hb + ((size_t)(e0 & 0x1FFFF) << 8));
    unsigned r1 = *(const unsigned*)(Hb + ((size_t)(e1 & 0x1FFFF) << 8));
    unsigned r2 = *(const unsigned*)(Hb + ((size_t)(e2 & 0x1FFFF) << 8));
    unsigned r3 = *(const unsigned*)(Hb + ((size_t)(e3 & 0x1FFFF) << 8));
    m = pk_max(m, *(h2*)&r0 * dec_w(e0));
    m = pk_max(m, *(h2*)&r1 * dec_w(e1));
    m = pk_max(m, *(h2*)&r2 * dec_w(e2));
    m = pk_max(m, *(h2*)&r3 * dec_w(e3));
  }
  for (; j < end; j += 4) {
    unsigned e0 = csr4[j];
    unsigned r0 = *(const unsigned*)(Hb + ((size_t)(e0 & 0x1FFFF) << 8));
    m = pk_max(m, *(h2*)&r0 * dec_w(e0));
  }
  #pragma unroll
  for (int d = 16; d <= 32; d <<= 1) {
    unsigned u = __shfl_xor(*(unsigned*)&m, d, 64);
    m = pk_max(m, *(h2*)&u);
  }
  if (q == 0) {
    float vx = (float)m.x, vy = (float)m.y;
    if (end == beg) { vx = 0.f; vy = 0.f; }  // dead (self-loops)
    float2 bb = *(const float2*)&bias[(c << 5) + (l4 << 1)];
    __half2 o = __floats2half2_rn(fmaxf(vx + bb.x, 0.f), fmaxf(vy + bb.y, 0.f));
    *(unsigned*)((char*)Xout + ((size_t)node << 8) + (c << 6) + (l4 << 2)) =
        *(unsigned*)&o;
  }
}

// ---------------------------------------------------------------- classifier + log_softmax
__global__ __launch_bounds__(256) void k_classifier(
    const __half* __restrict__ X, const float* __restrict__ Wc,
    const float* __restrict__ bc, float* __restrict__ out, int n) {
  __shared__ float sW[HID * NCLS];
  __shared__ float sx[8][HID];
  int tid = threadIdx.x;
  #pragma unroll
  for (int i = 0; i < 4; ++i)
    ((float4*)sW)[tid + 256 * i] = ((const float4*)Wc)[tid + 256 * i];
  int node0 = blockIdx.x * 8;
  {
    int r = tid >> 5, c = (tid & 31) << 2;
    if (node0 + r < n) {
      __half2 p0 = *(const __half2*)&X[(size_t)(node0 + r) * HID + c];
      __half2 p1 = *(const __half2*)&X[(size_t)(node0 + r) * HID + c + 2];
      float2 f0 = __half22float2(p0), f1 = __half22float2(p1);
      sx[r][c] = f0.x; sx[r][c + 1] = f0.y; sx[r][c + 2] = f1.x; sx[r][c + 3] = f1.y;
    }
  }
  __syncthreads();
  int g = tid >> 5, c = tid & 31;
  int node = node0 + g;
  if (node >= n) return;
  float acc = bc[c];
  #pragma unroll 8
  for (int k = 0; k < HID; ++k)
    acc = fmaf(sx[g][k], sW[k * NCLS + c], acc);
  float m = acc;
  #pragma unroll
  for (int off = 16; off; off >>= 1) m = fmaxf(m, __shfl_xor(m, off, 32));
  float e = expf(acc - m);
  float s = e;
  #pragma unroll
  for (int off = 16; off; off >>= 1) s += __shfl_xor(s, off, 32);
  out[(size_t)node * NCLS + c] = acc - m - logf(s);
}

// ---------------------------------------------------------------- launch
extern "C" void kernel_launch(void* const* d_in, const int* in_sizes, int n_in,
                              void* d_out, int out_size, void* d_ws, size_t ws_size,
                              hipStream_t stream) {
  const float* x    = (const float*)d_in[0];
  const int*   ei   = (const int*)d_in[1];
  const float* norm = (const float*)d_in[2];
  const float* Ws   = (const float*)d_in[3];
  const float* bs   = (const float*)d_in[4];
  const float* Wc   = (const float*)d_in[5];
  const float* bc   = (const float*)d_in[6];
  float* out = (float*)d_out;

  const int N = in_sizes[0] / HID;
  const int E = in_sizes[1] / 2;
  const int L = in_sizes[3] / (HID * HID);
  const int T = E + N;
  const int NB = (N + 511) >> 9;
  const int NG4 = (N + 3) >> 2;            // node groups of 4
  const int AGG_GRID = ((NG4 + 1) >> 1) * 8;

  char* p = (char*)d_ws;
  auto alloc = [&](size_t bytes) {
    char* r = p; p += (bytes + 255) & ~(size_t)255; return r;
  };
  __half*   xa         = (__half*)alloc((size_t)N * HID * 2);
  __half*   xb         = (__half*)alloc((size_t)N * HID * 2);
  __half*   hbuf       = (__half*)alloc((size_t)N * HID * 2);
  __half*   Wt         = (__half*)alloc((size_t)L * HID * HID * 2);
  int*      row_off    = (int*)alloc(((size_t)N + 1) * 4);
  int*      bucket_cur = (int*)alloc(256 * 4);
  int*      bucket_off = (int*)alloc(257 * 4);
  int2*     bins       = (int2*)alloc((size_t)NB * BCAP * 8);
  unsigned* csr4       = (unsigned*)alloc((size_t)T * 4);
  (void)ws_size; (void)n_in; (void)out_size;

  hipMemsetAsync(bucket_cur, 0, 256 * 4, stream);
  k_prep_x<<<(N * 32 + 255) / 256, 256, 0, stream>>>(x, xa, N * 32);
  k_prep_w<<<(L * HID * HID + 255) / 256, 256, 0, stream>>>(Ws, Wt, L * HID * HID);
  k_bin<<<(T + 8191) / 8192, 1024, 0, stream>>>(ei, norm, bucket_cur, bins, E, T);
  k_bscan<<<1, 256, 0, stream>>>(bucket_cur, bucket_off, NB);
  k_sortbucket<<<NB, 1024, 0, stream>>>(bins, bucket_off, csr4, row_off, N, NB);

  __half* xin = xa;
  __half* xout = xb;
  for (int l = 0; l < L; ++l) {
    k_gemm_mfma<<<(N + 63) / 64, 256, 0, stream>>>(
        xin, Wt + (size_t)l * HID * HID, hbuf, N);
    k_aggregate<<<AGG_GRID, 256, 0, stream>>>(
        hbuf, row_off, csr4, bs + (size_t)l * HID, xout, N);
    __half* tmp = xin; xin = xout; xout = tmp;
  }
  k_classifier<<<(N + 7) / 8, 256, 0, stream>>>(xin, Wc, bc, out, N);
}

// Round 11
// 324.193 us; speedup vs baseline: 2.0844x; 1.9316x over previous
//
#include <hip/hip_runtime.h>
#include <hip/hip_fp16.h>
#include <math.h>

#define HID 128
#define NCLS 32
#define BCAP 12288   // per-bucket capacity in bins (mean 8704, +38 sigma)
#define SCAP 9728    // LDS sort capacity (mean 8704, +11 sigma)
#define SLCSH 14     // src slice = src >> 14 (8 slices of 16K nodes)

typedef _Float16 half8 __attribute__((ext_vector_type(8)));
typedef _Float16 h2 __attribute__((ext_vector_type(2)));
typedef float f32x4 __attribute__((ext_vector_type(4)));

union hbits_u { unsigned short u; _Float16 f; };

__device__ __forceinline__ void gload_lds16(const void* g, void* l) {
  __builtin_amdgcn_global_load_lds(
      (const __attribute__((address_space(1))) void*)g,
      (__attribute__((address_space(3))) void*)l, 16, 0, 0);
}

__device__ __forceinline__ h2 pk_max(h2 a, h2 b) {
  return __builtin_elementwise_max(a, b);   // v_pk_max_f16
}

__device__ __forceinline__ _Float16 dec_w(unsigned e) {
  hbits_u u; u.u = (unsigned short)((e >> 16) & 0xFFFEu);
  return u.f;
}

// ---------------------------------------------------------------- prep
__global__ void k_prep_x(const float* __restrict__ x, __half* __restrict__ xa,
                         int total4) {
  int i = blockIdx.x * blockDim.x + threadIdx.x;
  if (i >= total4) return;
  float4 v = ((const float4*)x)[i];
  __half2* o = (__half2*)xa + i * 2;
  o[0] = __floats2half2_rn(v.x, v.y);
  o[1] = __floats2half2_rn(v.z, v.w);
}

__global__ void k_prep_w(const float* __restrict__ Ws, __half* __restrict__ Wt,
                         int total) {
  int i = blockIdx.x * blockDim.x + threadIdx.x;
  if (i >= total) return;
  int l = i >> 14, r = i & 16383;
  int nn = r >> 7, k = r & 127;
  Wt[i] = __float2half_rn(Ws[(l << 14) + k * HID + nn]);
}

// ---------------------------------------------------------------- binned CSR build
__global__ __launch_bounds__(1024) void k_bin(const int* __restrict__ ei,
                                              const float* __restrict__ norm,
                                              int* __restrict__ bucket_cur,
                                              int2* __restrict__ bins,
                                              int E, int T) {
  __shared__ int bcnt[256];
  __shared__ int bbase[256];
  int tid = threadIdx.x;
  if (tid < 256) bcnt[tid] = 0;
  __syncthreads();
  int base = blockIdx.x * 8192;
  int2 ent[8];
  int bk[8];
  #pragma unroll
  for (int i = 0; i < 8; ++i) {
    int e = base + (i << 10) + tid;
    bk[i] = -1;
    if (e < T) {
      int src, dst;
      if (e < E) { src = ei[e]; dst = ei[E + e]; } else { src = dst = e - E; }
      bk[i] = dst >> 9;
      ent[i] = make_int2(src | ((dst & 511) << 17), __float_as_int(norm[e]));
      atomicAdd(&bcnt[bk[i]], 1);
    }
  }
  __syncthreads();
  if (tid < 256) {
    int c = bcnt[tid];
    bbase[tid] = c ? atomicAdd(&bucket_cur[tid], c) : 0;
    bcnt[tid] = 0;
  }
  __syncthreads();
  #pragma unroll
  for (int i = 0; i < 8; ++i) {
    if (bk[i] >= 0) {
      int pos = bbase[bk[i]] + atomicAdd(&bcnt[bk[i]], 1);
      bins[(size_t)bk[i] * BCAP + pos] = ent[i];
    }
  }
}

__global__ __launch_bounds__(256) void k_bscan(const int* __restrict__ bucket_cur,
                                               int* __restrict__ bucket_off, int nb) {
  __shared__ int a[256];
  int tid = threadIdx.x;
  int orig = (tid < nb) ? bucket_cur[tid] : 0;
  a[tid] = orig;
  __syncthreads();
  for (int d = 1; d < 256; d <<= 1) {
    int t = (tid >= d) ? a[tid - d] : 0;
    __syncthreads();
    a[tid] += t;
    __syncthreads();
  }
  if (tid < nb) bucket_off[tid] = a[tid] - orig;
  if (tid == nb - 1) bucket_off[nb] = a[tid];
}

// per-bucket counting sort by (dstLocal, srcSlice): node-major lists with
// slice-ascending srcs inside each list. Emits row_off + packed 4B csr
// entries (src:17 | norm-fp15:15).
__global__ __launch_bounds__(1024) void k_sortbucket(
    const int2* __restrict__ bins, const int* __restrict__ bucket_off,
    unsigned* __restrict__ csr4, int* __restrict__ row_off, int n, int nb) {
  __shared__ unsigned sorted[SCAP];
  __shared__ int cnt_[4096];          // (dl<<3)|slice
  __shared__ int wsum[16];
  int b = blockIdx.x, tid = threadIdx.x;
  int goff = bucket_off[b];
  int cnt = bucket_off[b + 1] - goff;
  if (cnt > SCAP) cnt = SCAP;
  const int2* src = bins + (size_t)b * BCAP;
  int2 myent[10];
  int mykey[10];
  #pragma unroll
  for (int i = 0; i < 10; ++i) {
    int j = tid + (i << 10);
    if (j < cnt) {
      myent[i] = src[j];
      int s = myent[i].x & 0x1FFFF;
      int dl = ((unsigned)myent[i].x) >> 17;
      mykey[i] = (dl << 3) | (s >> SLCSH);
    }
  }
  #pragma unroll
  for (int i = 0; i < 4; ++i) cnt_[tid + (i << 10)] = 0;
  __syncthreads();
  #pragma unroll
  for (int i = 0; i < 10; ++i) {
    int j = tid + (i << 10);
    if (j < cnt) atomicAdd(&cnt_[mykey[i]], 1);
  }
  __syncthreads();
  // exclusive scan of 4096 bins: 4 consecutive bins per thread + block scan
  int base = tid << 2;
  int l0 = cnt_[base], l1 = cnt_[base + 1], l2 = cnt_[base + 2], l3 = cnt_[base + 3];
  int s0 = l0 + l1 + l2 + l3;
  int lane = tid & 63, wid = tid >> 6;
  int incl = s0;
  #pragma unroll
  for (int d = 1; d < 64; d <<= 1) {
    int t = __shfl_up(incl, d, 64);
    if (lane >= d) incl += t;
  }
  if (lane == 63) wsum[wid] = incl;
  __syncthreads();
  if (wid == 0 && lane < 16) {
    int wv = wsum[lane];
    int winc = wv;
    #pragma unroll
    for (int d = 1; d < 16; d <<= 1) {
      int t = __shfl_up(winc, d, 16);
      if (lane >= d) winc += t;
    }
    wsum[lane] = winc - wv;
  }
  __syncthreads();
  int excl = incl - s0 + wsum[wid];
  cnt_[base]     = excl;
  cnt_[base + 1] = excl + l0;
  cnt_[base + 2] = excl + l0 + l1;
  cnt_[base + 3] = excl + l0 + l1 + l2;
  __syncthreads();
  // row_off[node] = prefix at bin (dl<<3) -- before cursor pass mutates cnt_
  int node = (b << 9) + tid;
  if (tid < 512 && node < n) row_off[node] = goff + cnt_[tid << 3];
  if (b == nb - 1 && tid == 0) row_off[n] = bucket_off[nb];
  __syncthreads();
  #pragma unroll
  for (int i = 0; i < 10; ++i) {
    int j = tid + (i << 10);
    if (j < cnt) {
      int pos = atomicAdd(&cnt_[mykey[i]], 1);
      if (pos < SCAP) {
        __half h = __float2half_rn(__int_as_float(myent[i].y));
        unsigned short hb = *(unsigned short*)&h;
        sorted[pos] = (unsigned)(myent[i].x & 0x1FFFF) | ((unsigned)(hb >> 1) << 17);
      }
    }
  }
  __syncthreads();
  for (int j = tid; j < cnt; j += 1024) csr4[goff + j] = sorted[j];
}

// ---------------------------------------------------------------- MFMA GEMM (64-row config)
__global__ __launch_bounds__(256) void k_gemm_mfma(const __half* __restrict__ X,
                                                   const __half* __restrict__ Wl,
                                                   __half* __restrict__ H, int n) {
  __shared__ char lds[49152];
  char* ldsW = lds;
  char* ldsX = lds + 32768;
  int tid = threadIdx.x, lane = tid & 63, w = tid >> 6;
  int row0 = blockIdx.x * 64;
  int rows = n - row0; if (rows > 64) rows = 64;
  int vbytes = rows << 8;

  #pragma unroll
  for (int it = 0; it < 8; ++it) {
    int d = (w << 13) + (it << 10) + (lane << 4);
    int src = d ^ (((d >> 8) & 7) << 4);
    gload_lds16((const char*)Wl + src, ldsW + (w << 13) + (it << 10));
  }
  #pragma unroll
  for (int it = 0; it < 4; ++it) {
    int d = (w << 12) + (it << 10) + (lane << 4);
    if (d < vbytes) {
      int src = d ^ (((d >> 8) & 7) << 4);
      gload_lds16((const char*)X + ((size_t)row0 << 8) + src,
                  ldsX + (w << 12) + (it << 10));
    }
  }
  __syncthreads();

  int l15 = lane & 15, lhi = lane >> 4;
  half8 a[4];
  #pragma unroll
  for (int s = 0; s < 4; ++s) {
    int m = (w << 4) + l15;
    int d = (m << 8) + (s << 6) + (lhi << 4);
    a[s] = *(const half8*)(ldsX + (d ^ ((m & 7) << 4)));
  }
  f32x4 acc[8] = {};
  #pragma unroll
  for (int s = 0; s < 4; ++s) {
    #pragma unroll
    for (int t = 0; t < 8; ++t) {
      int nn = (t << 4) + l15;
      int d = (nn << 8) + (s << 6) + (lhi << 4);
      half8 b = *(const half8*)(ldsW + (d ^ ((nn & 7) << 4)));
      acc[t] = __builtin_amdgcn_mfma_f32_16x16x32_f16(a[s], b, acc[t], 0, 0, 0);
    }
  }
  #pragma unroll
  for (int t = 0; t < 8; ++t) {
    int col = (t << 4) + l15;
    #pragma unroll
    for (int r = 0; r < 4; ++r) {
      int row = row0 + (w << 4) + (lhi << 2) + r;
      if (row < n) H[(size_t)row * HID + col] = __float2half_rn(acc[t][r]);
    }
  }
}

// ---------------------------------------------------------------- aggregate
// wave per node, full 256B row per edge (quarter-wave x 16B), 16 edges in
// flight, packed fp16 math, 4B csr entries, slice-sorted edge lists.
__global__ __launch_bounds__(256) void k_aggregate(
    const __half* __restrict__ H, const int* __restrict__ row_off,
    const unsigned* __restrict__ csr4, const float* __restrict__ bias,
    __half* __restrict__ Xout, int n) {
  int node = (int)((blockIdx.x * blockDim.x + threadIdx.x) >> 6);
  if (node >= n) return;
  int lane = threadIdx.x & 63;
  int q = lane >> 4, l4 = lane & 15;
  int beg = row_off[node], end = row_off[node + 1];
  const char* Hb = (const char*)H + (l4 << 4);
  const unsigned NEG = 0xFC00FC00u;
  h2 m0 = *(const h2*)&NEG, m1 = m0, m2 = m0, m3 = m0;
  int j = beg + q;
  for (; j + 12 < end; j += 16) {
    unsigned e0 = csr4[j], e1 = csr4[j + 4], e2 = csr4[j + 8], e3 = csr4[j + 12];
    _Float16 w0 = dec_w(e0), w1 = dec_w(e1), w2 = dec_w(e2), w3 = dec_w(e3);
    uint4 r0 = *(const uint4*)(Hb + ((size_t)(e0 & 0x1FFFF) << 8));
    uint4 r1 = *(const uint4*)(Hb + ((size_t)(e1 & 0x1FFFF) << 8));
    uint4 r2 = *(const uint4*)(Hb + ((size_t)(e2 & 0x1FFFF) << 8));
    uint4 r3 = *(const uint4*)(Hb + ((size_t)(e3 & 0x1FFFF) << 8));
    m0 = pk_max(m0, *(h2*)&r0.x * w0);
    m1 = pk_max(m1, *(h2*)&r0.y * w0);
    m2 = pk_max(m2, *(h2*)&r0.z * w0);
    m3 = pk_max(m3, *(h2*)&r0.w * w0);
    m0 = pk_max(m0, *(h2*)&r1.x * w1);
    m1 = pk_max(m1, *(h2*)&r1.y * w1);
    m2 = pk_max(m2, *(h2*)&r1.z * w1);
    m3 = pk_max(m3, *(h2*)&r1.w * w1);
    m0 = pk_max(m0, *(h2*)&r2.x * w2);
    m1 = pk_max(m1, *(h2*)&r2.y * w2);
    m2 = pk_max(m2, *(h2*)&r2.z * w2);
    m3 = pk_max(m3, *(h2*)&r2.w * w2);
    m0 = pk_max(m0, *(h2*)&r3.x * w3);
    m1 = pk_max(m1, *(h2*)&r3.y * w3);
    m2 = pk_max(m2, *(h2*)&r3.z * w3);
    m3 = pk_max(m3, *(h2*)&r3.w * w3);
  }
  for (; j < end; j += 4) {
    unsigned e0 = csr4[j];
    _Float16 w0 = dec_w(e0);
    uint4 r0 = *(const uint4*)(Hb + ((size_t)(e0 & 0x1FFFF) << 8));
    m0 = pk_max(m0, *(h2*)&r0.x * w0);
    m1 = pk_max(m1, *(h2*)&r0.y * w0);
    m2 = pk_max(m2, *(h2*)&r0.z * w0);
    m3 = pk_max(m3, *(h2*)&r0.w * w0);
  }
  #pragma unroll
  for (int d = 16; d <= 32; d <<= 1) {
    unsigned u0 = __shfl_xor(*(unsigned*)&m0, d, 64);
    unsigned u1 = __shfl_xor(*(unsigned*)&m1, d, 64);
    unsigned u2 = __shfl_xor(*(unsigned*)&m2, d, 64);
    unsigned u3 = __shfl_xor(*(unsigned*)&m3, d, 64);
    m0 = pk_max(m0, *(h2*)&u0);
    m1 = pk_max(m1, *(h2*)&u1);
    m2 = pk_max(m2, *(h2*)&u2);
    m3 = pk_max(m3, *(h2*)&u3);
  }
  if (q == 0) {
    float f0x = (float)m0.x, f0y = (float)m0.y;
    float f1x = (float)m1.x, f1y = (float)m1.y;
    float f2x = (float)m2.x, f2y = (float)m2.y;
    float f3x = (float)m3.x, f3y = (float)m3.y;
    if (end == beg) {  // dead (self-loops guarantee deg>=1)
      f0x=f0y=f1x=f1y=f2x=f2y=f3x=f3y = 0.f;
    }
    float4 b0 = ((const float4*)bias)[l4 << 1];
    float4 b1 = ((const float4*)bias)[(l4 << 1) + 1];
    __half2 o0 = __floats2half2_rn(fmaxf(f0x + b0.x, 0.f), fmaxf(f0y + b0.y, 0.f));
    __half2 o1 = __floats2half2_rn(fmaxf(f1x + b0.z, 0.f), fmaxf(f1y + b0.w, 0.f));
    __half2 o2 = __floats2half2_rn(fmaxf(f2x + b1.x, 0.f), fmaxf(f2y + b1.y, 0.f));
    __half2 o3 = __floats2half2_rn(fmaxf(f3x + b1.z, 0.f), fmaxf(f3y + b1.w, 0.f));
    uint4 ov = make_uint4(*(unsigned*)&o0, *(unsigned*)&o1,
                          *(unsigned*)&o2, *(unsigned*)&o3);
    *(uint4*)((char*)Xout + ((size_t)node << 8) + (l4 << 4)) = ov;
  }
}

// ---------------------------------------------------------------- classifier + log_softmax
__global__ __launch_bounds__(256) void k_classifier(
    const __half* __restrict__ X, const float* __restrict__ Wc,
    const float* __restrict__ bc, float* __restrict__ out, int n) {
  __shared__ float sW[HID * NCLS];
  __shared__ float sx[8][HID];
  int tid = threadIdx.x;
  #pragma unroll
  for (int i = 0; i < 4; ++i)
    ((float4*)sW)[tid + 256 * i] = ((const float4*)Wc)[tid + 256 * i];
  int node0 = blockIdx.x * 8;
  {
    int r = tid >> 5, c = (tid & 31) << 2;
    if (node0 + r < n) {
      __half2 p0 = *(const __half2*)&X[(size_t)(node0 + r) * HID + c];
      __half2 p1 = *(const __half2*)&X[(size_t)(node0 + r) * HID + c + 2];
      float2 f0 = __half22float2(p0), f1 = __half22float2(p1);
      sx[r][c] = f0.x; sx[r][c + 1] = f0.y; sx[r][c + 2] = f1.x; sx[r][c + 3] = f1.y;
    }
  }
  __syncthreads();
  int g = tid >> 5, c = tid & 31;
  int node = node0 + g;
  if (node >= n) return;
  float acc = bc[c];
  #pragma unroll 8
  for (int k = 0; k < HID; ++k)
    acc = fmaf(sx[g][k], sW[k * NCLS + c], acc);
  float m = acc;
  #pragma unroll
  for (int off = 16; off; off >>= 1) m = fmaxf(m, __shfl_xor(m, off, 32));
  float e = expf(acc - m);
  float s = e;
  #pragma unroll
  for (int off = 16; off; off >>= 1) s += __shfl_xor(s, off, 32);
  out[(size_t)node * NCLS + c] = acc - m - logf(s);
}

// ---------------------------------------------------------------- launch
extern "C" void kernel_launch(void* const* d_in, const int* in_sizes, int n_in,
                              void* d_out, int out_size, void* d_ws, size_t ws_size,
                              hipStream_t stream) {
  const float* x    = (const float*)d_in[0];
  const int*   ei   = (const int*)d_in[1];
  const float* norm = (const float*)d_in[2];
  const float* Ws   = (const float*)d_in[3];
  const float* bs   = (const float*)d_in[4];
  const float* Wc   = (const float*)d_in[5];
  const float* bc   = (const float*)d_in[6];
  float* out = (float*)d_out;

  const int N = in_sizes[0] / HID;
  const int E = in_sizes[1] / 2;
  const int L = in_sizes[3] / (HID * HID);
  const int T = E + N;
  const int NB = (N + 511) >> 9;

  char* p = (char*)d_ws;
  auto alloc = [&](size_t bytes) {
    char* r = p; p += (bytes + 255) & ~(size_t)255; return r;
  };
  __half*   xa         = (__half*)alloc((size_t)N * HID * 2);
  __half*   xb         = (__half*)alloc((size_t)N * HID * 2);
  __half*   hbuf       = (__half*)alloc((size_t)N * HID * 2);
  __half*   Wt         = (__half*)alloc((size_t)L * HID * HID * 2);
  int*      row_off    = (int*)alloc(((size_t)N + 1) * 4);
  int*      bucket_cur = (int*)alloc(256 * 4);
  int*      bucket_off = (int*)alloc(257 * 4);
  int2*     bins       = (int2*)alloc((size_t)NB * BCAP * 8);
  unsigned* csr4       = (unsigned*)alloc((size_t)T * 4);
  (void)ws_size; (void)n_in; (void)out_size;

  hipMemsetAsync(bucket_cur, 0, 256 * 4, stream);
  k_prep_x<<<(N * 32 + 255) / 256, 256, 0, stream>>>(x, xa, N * 32);
  k_prep_w<<<(L * HID * HID + 255) / 256, 256, 0, stream>>>(Ws, Wt, L * HID * HID);
  k_bin<<<(T + 8191) / 8192, 1024, 0, stream>>>(ei, norm, bucket_cur, bins, E, T);
  k_bscan<<<1, 256, 0, stream>>>(bucket_cur, bucket_off, NB);
  k_sortbucket<<<NB, 1024, 0, stream>>>(bins, bucket_off, csr4, row_off, N, NB);

  __half* xin = xa;
  __half* xout = xb;
  for (int l = 0; l < L; ++l) {
    k_gemm_mfma<<<(N + 63) / 64, 256, 0, stream>>>(
        xin, Wt + (size_t)l * HID * HID, hbuf, N);
    k_aggregate<<<(N + 3) / 4, 256, 0, stream>>>(
        hbuf, row_off, csr4, bs + (size_t)l * HID, xout, N);
    __half* tmp = xin; xin = xout; xout = tmp;
  }
  k_classifier<<<(N + 7) / 8, 256, 0, stream>>>(xin, Wc, bc, out, N);
}

// Round 12
// 313.616 us; speedup vs baseline: 2.1547x; 1.0337x over previous
//
#include <hip/hip_runtime.h>
#include <hip/hip_fp16.h>
#include <math.h>

#define HID 128
#define NCLS 32
#define BCAP 12288   // per-bucket capacity in bins (mean 8704, +38 sigma)
#define SCAP 9728    // LDS sort capacity (mean 8704, +11 sigma)
#define SLCSH 14     // src slice = src >> 14

typedef _Float16 half8 __attribute__((ext_vector_type(8)));
typedef _Float16 h2 __attribute__((ext_vector_type(2)));
typedef float f32x4 __attribute__((ext_vector_type(4)));

union hbits_u { unsigned short u; _Float16 f; };

__device__ __forceinline__ void gload_lds16(const void* g, void* l) {
  __builtin_amdgcn_global_load_lds(
      (const __attribute__((address_space(1))) void*)g,
      (__attribute__((address_space(3))) void*)l, 16, 0, 0);
}

__device__ __forceinline__ h2 pk_max(h2 a, h2 b) {
  return __builtin_elementwise_max(a, b);   // v_pk_max_f16
}

__device__ __forceinline__ _Float16 dec_w(unsigned e) {
  hbits_u u; u.u = (unsigned short)((e >> 16) & 0xFFFEu);
  return u.f;
}

// ---------------------------------------------------------------- prep (W only)
__global__ void k_prep_w(const float* __restrict__ Ws, __half* __restrict__ Wt,
                         int total) {
  int i = blockIdx.x * blockDim.x + threadIdx.x;
  if (i >= total) return;
  int l = i >> 14, r = i & 16383;
  int nn = r >> 7, k = r & 127;
  Wt[i] = __float2half_rn(Ws[(l << 14) + k * HID + nn]);
}

// ---------------------------------------------------------------- binned CSR build
__global__ __launch_bounds__(1024) void k_bin(const int* __restrict__ ei,
                                              const float* __restrict__ norm,
                                              int* __restrict__ bucket_cur,
                                              int2* __restrict__ bins,
                                              int E, int T) {
  __shared__ int bcnt[256];
  __shared__ int bbase[256];
  int tid = threadIdx.x;
  if (tid < 256) bcnt[tid] = 0;
  __syncthreads();
  int base = blockIdx.x * 8192;
  int2 ent[8];
  int bk[8];
  #pragma unroll
  for (int i = 0; i < 8; ++i) {
    int e = base + (i << 10) + tid;
    bk[i] = -1;
    if (e < T) {
      int src, dst;
      if (e < E) { src = ei[e]; dst = ei[E + e]; } else { src = dst = e - E; }
      bk[i] = dst >> 9;
      ent[i] = make_int2(src | ((dst & 511) << 17), __float_as_int(norm[e]));
      atomicAdd(&bcnt[bk[i]], 1);
    }
  }
  __syncthreads();
  if (tid < 256) {
    int c = bcnt[tid];
    bbase[tid] = c ? atomicAdd(&bucket_cur[tid], c) : 0;
    bcnt[tid] = 0;
  }
  __syncthreads();
  #pragma unroll
  for (int i = 0; i < 8; ++i) {
    if (bk[i] >= 0) {
      int pos = bbase[bk[i]] + atomicAdd(&bcnt[bk[i]], 1);
      bins[(size_t)bk[i] * BCAP + pos] = ent[i];
    }
  }
}

__global__ __launch_bounds__(256) void k_bscan(const int* __restrict__ bucket_cur,
                                               int* __restrict__ bucket_off, int nb) {
  __shared__ int a[256];
  int tid = threadIdx.x;
  int orig = (tid < nb) ? bucket_cur[tid] : 0;
  a[tid] = orig;
  __syncthreads();
  for (int d = 1; d < 256; d <<= 1) {
    int t = (tid >= d) ? a[tid - d] : 0;
    __syncthreads();
    a[tid] += t;
    __syncthreads();
  }
  if (tid < nb) bucket_off[tid] = a[tid] - orig;
  if (tid == nb - 1) bucket_off[nb] = a[tid];
}

// per-bucket counting sort by (dstLocal, srcSlice); emits row_off + 4B csr.
__global__ __launch_bounds__(1024) void k_sortbucket(
    const int2* __restrict__ bins, const int* __restrict__ bucket_off,
    unsigned* __restrict__ csr4, int* __restrict__ row_off, int n, int nb) {
  __shared__ unsigned sorted[SCAP];
  __shared__ int cnt_[4096];
  __shared__ int wsum[16];
  int b = blockIdx.x, tid = threadIdx.x;
  int goff = bucket_off[b];
  int cnt = bucket_off[b + 1] - goff;
  if (cnt > SCAP) cnt = SCAP;
  const int2* src = bins + (size_t)b * BCAP;
  int2 myent[10];
  int mykey[10];
  #pragma unroll
  for (int i = 0; i < 10; ++i) {
    int j = tid + (i << 10);
    if (j < cnt) {
      myent[i] = src[j];
      int s = myent[i].x & 0x1FFFF;
      int dl = ((unsigned)myent[i].x) >> 17;
      mykey[i] = (dl << 3) | (s >> SLCSH);
    }
  }
  #pragma unroll
  for (int i = 0; i < 4; ++i) cnt_[tid + (i << 10)] = 0;
  __syncthreads();
  #pragma unroll
  for (int i = 0; i < 10; ++i) {
    int j = tid + (i << 10);
    if (j < cnt) atomicAdd(&cnt_[mykey[i]], 1);
  }
  __syncthreads();
  int base = tid << 2;
  int l0 = cnt_[base], l1 = cnt_[base + 1], l2 = cnt_[base + 2], l3 = cnt_[base + 3];
  int s0 = l0 + l1 + l2 + l3;
  int lane = tid & 63, wid = tid >> 6;
  int incl = s0;
  #pragma unroll
  for (int d = 1; d < 64; d <<= 1) {
    int t = __shfl_up(incl, d, 64);
    if (lane >= d) incl += t;
  }
  if (lane == 63) wsum[wid] = incl;
  __syncthreads();
  if (wid == 0 && lane < 16) {
    int wv = wsum[lane];
    int winc = wv;
    #pragma unroll
    for (int d = 1; d < 16; d <<= 1) {
      int t = __shfl_up(winc, d, 16);
      if (lane >= d) winc += t;
    }
    wsum[lane] = winc - wv;
  }
  __syncthreads();
  int excl = incl - s0 + wsum[wid];
  cnt_[base]     = excl;
  cnt_[base + 1] = excl + l0;
  cnt_[base + 2] = excl + l0 + l1;
  cnt_[base + 3] = excl + l0 + l1 + l2;
  __syncthreads();
  int node = (b << 9) + tid;
  if (tid < 512 && node < n) row_off[node] = goff + cnt_[tid << 3];
  if (b == nb - 1 && tid == 0) row_off[n] = bucket_off[nb];
  __syncthreads();
  #pragma unroll
  for (int i = 0; i < 10; ++i) {
    int j = tid + (i << 10);
    if (j < cnt) {
      int pos = atomicAdd(&cnt_[mykey[i]], 1);
      if (pos < SCAP) {
        __half h = __float2half_rn(__int_as_float(myent[i].y));
        unsigned short hb = *(unsigned short*)&h;
        sorted[pos] = (unsigned)(myent[i].x & 0x1FFFF) | ((unsigned)(hb >> 1) << 17);
      }
    }
  }
  __syncthreads();
  for (int j = tid; j < cnt; j += 1024) csr4[goff + j] = sorted[j];
}

// ---------------------------------------------------------------- MFMA GEMM (fp16 input)
// 64 rows/block; coalesced epilogue via LDS restage.
__global__ __launch_bounds__(256) void k_gemm_mfma(const __half* __restrict__ X,
                                                   const __half* __restrict__ Wl,
                                                   __half* __restrict__ H, int n) {
  __shared__ char lds[49152];
  char* ldsW = lds;
  char* ldsX = lds + 32768;    // 16KB X tile; reused for epilogue staging
  int tid = threadIdx.x, lane = tid & 63, w = tid >> 6;
  int row0 = blockIdx.x * 64;
  int rows = n - row0; if (rows > 64) rows = 64;
  int vbytes = rows << 8;

  #pragma unroll
  for (int it = 0; it < 8; ++it) {
    int d = (w << 13) + (it << 10) + (lane << 4);
    int src = d ^ (((d >> 8) & 7) << 4);
    gload_lds16((const char*)Wl + src, ldsW + (w << 13) + (it << 10));
  }
  #pragma unroll
  for (int it = 0; it < 4; ++it) {
    int d = (w << 12) + (it << 10) + (lane << 4);
    if (d < vbytes) {
      int src = d ^ (((d >> 8) & 7) << 4);
      gload_lds16((const char*)X + ((size_t)row0 << 8) + src,
                  ldsX + (w << 12) + (it << 10));
    }
  }
  __syncthreads();

  int l15 = lane & 15, lhi = lane >> 4;
  half8 a[4];
  #pragma unroll
  for (int s = 0; s < 4; ++s) {
    int m = (w << 4) + l15;
    int d = (m << 8) + (s << 6) + (lhi << 4);
    a[s] = *(const half8*)(ldsX + (d ^ ((m & 7) << 4)));
  }
  __syncthreads();   // all A-frags consumed before ldsX reuse
  f32x4 acc[8] = {};
  #pragma unroll
  for (int s = 0; s < 4; ++s) {
    #pragma unroll
    for (int t = 0; t < 8; ++t) {
      int nn = (t << 4) + l15;
      int d = (nn << 8) + (s << 6) + (lhi << 4);
      half8 b = *(const half8*)(ldsW + (d ^ ((nn & 7) << 4)));
      acc[t] = __builtin_amdgcn_mfma_f32_16x16x32_f16(a[s], b, acc[t], 0, 0, 0);
    }
  }
  // epilogue: fp16 tile -> ldsX (swizzled), then coalesced uint4 stores
  #pragma unroll
  for (int t = 0; t < 8; ++t) {
    #pragma unroll
    for (int r = 0; r < 4; ++r) {
      int row = (w << 4) + (lhi << 2) + r;
      int byt = (row << 8) + (t << 5) + (l15 << 1);
      *(__half*)(ldsX + (byt ^ ((row & 7) << 4))) = __float2half_rn(acc[t][r]);
    }
  }
  __syncthreads();
  #pragma unroll
  for (int it = 0; it < 4; ++it) {
    int g = ((it << 8) + tid) << 4;          // 16B chunk, wave-contiguous
    if (g < vbytes) {
      uint4 v = *(const uint4*)(ldsX + (g ^ (((g >> 8) & 7) << 4)));
      *(uint4*)((char*)H + ((size_t)row0 << 8) + g) = v;
    }
  }
}

// ---------------------------------------------------------------- MFMA GEMM (fp32 input, layer 1)
// reads fp32 x directly; converts to fp16 in-register (identical numerics to
// prep_x + fp16 gemm). LDS: W 32KB + X-f32 32KB.
__global__ __launch_bounds__(256) void k_gemm_mfma_f32(const float* __restrict__ X,
                                                       const __half* __restrict__ Wl,
                                                       __half* __restrict__ H, int n) {
  __shared__ char lds[65536];
  char* ldsW = lds;
  char* ldsX = lds + 32768;    // 32KB fp32 X tile; front 16KB reused for epilogue
  int tid = threadIdx.x, lane = tid & 63, w = tid >> 6;
  int row0 = blockIdx.x * 64;
  int rows = n - row0; if (rows > 64) rows = 64;
  int vbytes32 = rows << 9;    // fp32 row = 512B
  int vbytes = rows << 8;      // fp16 out row = 256B

  #pragma unroll
  for (int it = 0; it < 8; ++it) {
    int d = (w << 13) + (it << 10) + (lane << 4);
    int src = d ^ (((d >> 8) & 7) << 4);
    gload_lds16((const char*)Wl + src, ldsW + (w << 13) + (it << 10));
  }
  #pragma unroll
  for (int it = 0; it < 8; ++it) {
    int d = (w << 13) + (it << 10) + (lane << 4);
    if (d < vbytes32) {
      int src = d ^ (((d >> 9) & 7) << 4);
      gload_lds16((const char*)X + ((size_t)row0 << 9) + src,
                  ldsX + (w << 13) + (it << 10));
    }
  }
  __syncthreads();

  int l15 = lane & 15, lhi = lane >> 4;
  half8 a[4];
  #pragma unroll
  for (int s = 0; s < 4; ++s) {
    int m = (w << 4) + l15;
    int d0 = (m << 9) + (s << 7) + (lhi << 5);
    int x0 = d0 ^ (((d0 >> 9) & 7) << 4);
    int d1 = d0 + 16;
    int x1 = d1 ^ (((d1 >> 9) & 7) << 4);
    float4 lo = *(const float4*)(ldsX + x0);
    float4 hi = *(const float4*)(ldsX + x1);
    half8 af;
    af[0] = (_Float16)lo.x; af[1] = (_Float16)lo.y;
    af[2] = (_Float16)lo.z; af[3] = (_Float16)lo.w;
    af[4] = (_Float16)hi.x; af[5] = (_Float16)hi.y;
    af[6] = (_Float16)hi.z; af[7] = (_Float16)hi.w;
    a[s] = af;
  }
  __syncthreads();
  f32x4 acc[8] = {};
  #pragma unroll
  for (int s = 0; s < 4; ++s) {
    #pragma unroll
    for (int t = 0; t < 8; ++t) {
      int nn = (t << 4) + l15;
      int d = (nn << 8) + (s << 6) + (lhi << 4);
      half8 b = *(const half8*)(ldsW + (d ^ ((nn & 7) << 4)));
      acc[t] = __builtin_amdgcn_mfma_f32_16x16x32_f16(a[s], b, acc[t], 0, 0, 0);
    }
  }
  #pragma unroll
  for (int t = 0; t < 8; ++t) {
    #pragma unroll
    for (int r = 0; r < 4; ++r) {
      int row = (w << 4) + (lhi << 2) + r;
      int byt = (row << 8) + (t << 5) + (l15 << 1);
      *(__half*)(ldsX + (byt ^ ((row & 7) << 4))) = __float2half_rn(acc[t][r]);
    }
  }
  __syncthreads();
  #pragma unroll
  for (int it = 0; it < 4; ++it) {
    int g = ((it << 8) + tid) << 4;
    if (g < vbytes) {
      uint4 v = *(const uint4*)(ldsX + (g ^ (((g >> 8) & 7) << 4)));
      *(uint4*)((char*)H + ((size_t)row0 << 8) + g) = v;
    }
  }
}

// ---------------------------------------------------------------- aggregate
// wave per node, quarter-wave x 16B per edge, 16 edges in flight, packed fp16.
__global__ __launch_bounds__(256) void k_aggregate(
    const __half* __restrict__ H, const int* __restrict__ row_off,
    const unsigned* __restrict__ csr4, const float* __restrict__ bias,
    __half* __restrict__ Xout, int n) {
  int node = (int)((blockIdx.x * blockDim.x + threadIdx.x) >> 6);
  if (node >= n) return;
  int lane = threadIdx.x & 63;
  int q = lane >> 4, l4 = lane & 15;
  int beg = row_off[node], end = row_off[node + 1];
  const char* Hb = (const char*)H + (l4 << 4);
  const unsigned NEG = 0xFC00FC00u;
  h2 m0 = *(const h2*)&NEG, m1 = m0, m2 = m0, m3 = m0;
  int j = beg + q;
  for (; j + 12 < end; j += 16) {
    unsigned e0 = csr4[j], e1 = csr4[j + 4], e2 = csr4[j + 8], e3 = csr4[j + 12];
    _Float16 w0 = dec_w(e0), w1 = dec_w(e1), w2 = dec_w(e2), w3 = dec_w(e3);
    uint4 r0 = *(const uint4*)(Hb + ((size_t)(e0 & 0x1FFFF) << 8));
    uint4 r1 = *(const uint4*)(Hb + ((size_t)(e1 & 0x1FFFF) << 8));
    uint4 r2 = *(const uint4*)(Hb + ((size_t)(e2 & 0x1FFFF) << 8));
    uint4 r3 = *(const uint4*)(Hb + ((size_t)(e3 & 0x1FFFF) << 8));
    m0 = pk_max(m0, *(h2*)&r0.x * w0);
    m1 = pk_max(m1, *(h2*)&r0.y * w0);
    m2 = pk_max(m2, *(h2*)&r0.z * w0);
    m3 = pk_max(m3, *(h2*)&r0.w * w0);
    m0 = pk_max(m0, *(h2*)&r1.x * w1);
    m1 = pk_max(m1, *(h2*)&r1.y * w1);
    m2 = pk_max(m2, *(h2*)&r1.z * w1);
    m3 = pk_max(m3, *(h2*)&r1.w * w1);
    m0 = pk_max(m0, *(h2*)&r2.x * w2);
    m1 = pk_max(m1, *(h2*)&r2.y * w2);
    m2 = pk_max(m2, *(h2*)&r2.z * w2);
    m3 = pk_max(m3, *(h2*)&r2.w * w2);
    m0 = pk_max(m0, *(h2*)&r3.x * w3);
    m1 = pk_max(m1, *(h2*)&r3.y * w3);
    m2 = pk_max(m2, *(h2*)&r3.z * w3);
    m3 = pk_max(m3, *(h2*)&r3.w * w3);
  }
  for (; j < end; j += 4) {
    unsigned e0 = csr4[j];
    _Float16 w0 = dec_w(e0);
    uint4 r0 = *(const uint4*)(Hb + ((size_t)(e0 & 0x1FFFF) << 8));
    m0 = pk_max(m0, *(h2*)&r0.x * w0);
    m1 = pk_max(m1, *(h2*)&r0.y * w0);
    m2 = pk_max(m2, *(h2*)&r0.z * w0);
    m3 = pk_max(m3, *(h2*)&r0.w * w0);
  }
  #pragma unroll
  for (int d = 16; d <= 32; d <<= 1) {
    unsigned u0 = __shfl_xor(*(unsigned*)&m0, d, 64);
    unsigned u1 = __shfl_xor(*(unsigned*)&m1, d, 64);
    unsigned u2 = __shfl_xor(*(unsigned*)&m2, d, 64);
    unsigned u3 = __shfl_xor(*(unsigned*)&m3, d, 64);
    m0 = pk_max(m0, *(h2*)&u0);
    m1 = pk_max(m1, *(h2*)&u1);
    m2 = pk_max(m2, *(h2*)&u2);
    m3 = pk_max(m3, *(h2*)&u3);
  }
  if (q == 0) {
    float f0x = (float)m0.x, f0y = (float)m0.y;
    float f1x = (float)m1.x, f1y = (float)m1.y;
    float f2x = (float)m2.x, f2y = (float)m2.y;
    float f3x = (float)m3.x, f3y = (float)m3.y;
    if (end == beg) {  // dead (self-loops guarantee deg>=1)
      f0x=f0y=f1x=f1y=f2x=f2y=f3x=f3y = 0.f;
    }
    float4 b0 = ((const float4*)bias)[l4 << 1];
    float4 b1 = ((const float4*)bias)[(l4 << 1) + 1];
    __half2 o0 = __floats2half2_rn(fmaxf(f0x + b0.x, 0.f), fmaxf(f0y + b0.y, 0.f));
    __half2 o1 = __floats2half2_rn(fmaxf(f1x + b0.z, 0.f), fmaxf(f1y + b0.w, 0.f));
    __half2 o2 = __floats2half2_rn(fmaxf(f2x + b1.x, 0.f), fmaxf(f2y + b1.y, 0.f));
    __half2 o3 = __floats2half2_rn(fmaxf(f3x + b1.z, 0.f), fmaxf(f3y + b1.w, 0.f));
    uint4 ov = make_uint4(*(unsigned*)&o0, *(unsigned*)&o1,
                          *(unsigned*)&o2, *(unsigned*)&o3);
    *(uint4*)((char*)Xout + ((size_t)node << 8) + (l4 << 4)) = ov;
  }
}

// ---------------------------------------------------------------- classifier + log_softmax
__global__ __launch_bounds__(256) void k_classifier(
    const __half* __restrict__ X, const float* __restrict__ Wc,
    const float* __restrict__ bc, float* __restrict__ out, int n) {
  __shared__ float sW[HID * NCLS];
  __shared__ float sx[8][HID];
  int tid = threadIdx.x;
  #pragma unroll
  for (int i = 0; i < 4; ++i)
    ((float4*)sW)[tid + 256 * i] = ((const float4*)Wc)[tid + 256 * i];
  int node0 = blockIdx.x * 8;
  {
    int r = tid >> 5, c = (tid & 31) << 2;
    if (node0 + r < n) {
      __half2 p0 = *(const __half2*)&X[(size_t)(node0 + r) * HID + c];
      __half2 p1 = *(const __half2*)&X[(size_t)(node0 + r) * HID + c + 2];
      float2 f0 = __half22float2(p0), f1 = __half22float2(p1);
      sx[r][c] = f0.x; sx[r][c + 1] = f0.y; sx[r][c + 2] = f1.x; sx[r][c + 3] = f1.y;
    }
  }
  __syncthreads();
  int g = tid >> 5, c = tid & 31;
  int node = node0 + g;
  if (node >= n) return;
  float acc = bc[c];
  #pragma unroll 8
  for (int k = 0; k < HID; ++k)
    acc = fmaf(sx[g][k], sW[k * NCLS + c], acc);
  float m = acc;
  #pragma unroll
  for (int off = 16; off; off >>= 1) m = fmaxf(m, __shfl_xor(m, off, 32));
  float e = expf(acc - m);
  float s = e;
  #pragma unroll
  for (int off = 16; off; off >>= 1) s += __shfl_xor(s, off, 32);
  out[(size_t)node * NCLS + c] = acc - m - logf(s);
}

// ---------------------------------------------------------------- launch
extern "C" void kernel_launch(void* const* d_in, const int* in_sizes, int n_in,
                              void* d_out, int out_size, void* d_ws, size_t ws_size,
                              hipStream_t stream) {
  const float* x    = (const float*)d_in[0];
  const int*   ei   = (const int*)d_in[1];
  const float* norm = (const float*)d_in[2];
  const float* Ws   = (const float*)d_in[3];
  const float* bs   = (const float*)d_in[4];
  const float* Wc   = (const float*)d_in[5];
  const float* bc   = (const float*)d_in[6];
  float* out = (float*)d_out;

  const int N = in_sizes[0] / HID;
  const int E = in_sizes[1] / 2;
  const int L = in_sizes[3] / (HID * HID);
  const int T = E + N;
  const int NB = (N + 511) >> 9;

  char* p = (char*)d_ws;
  auto alloc = [&](size_t bytes) {
    char* r = p; p += (bytes + 255) & ~(size_t)255; return r;
  };
  __half*   xb0        = (__half*)alloc((size_t)N * HID * 2);
  __half*   xb1        = (__half*)alloc((size_t)N * HID * 2);
  __half*   hbuf       = (__half*)alloc((size_t)N * HID * 2);
  __half*   Wt         = (__half*)alloc((size_t)L * HID * HID * 2);
  int*      row_off    = (int*)alloc(((size_t)N + 1) * 4);
  int*      bucket_cur = (int*)alloc(256 * 4);
  int*      bucket_off = (int*)alloc(257 * 4);
  int2*     bins       = (int2*)alloc((size_t)NB * BCAP * 8);
  unsigned* csr4       = (unsigned*)alloc((size_t)T * 4);
  (void)ws_size; (void)n_in; (void)out_size;

  hipMemsetAsync(bucket_cur, 0, 256 * 4, stream);
  k_prep_w<<<(L * HID * HID + 255) / 256, 256, 0, stream>>>(Ws, Wt, L * HID * HID);
  k_bin<<<(T + 8191) / 8192, 1024, 0, stream>>>(ei, norm, bucket_cur, bins, E, T);
  k_bscan<<<1, 256, 0, stream>>>(bucket_cur, bucket_off, NB);
  k_sortbucket<<<NB, 1024, 0, stream>>>(bins, bucket_off, csr4, row_off, N, NB);

  const int GB = (N + 63) / 64;
  // layer 1: fp32 x directly
  k_gemm_mfma_f32<<<GB, 256, 0, stream>>>(x, Wt, hbuf, N);
  k_aggregate<<<(N + 3) / 4, 256, 0, stream>>>(
      hbuf, row_off, csr4, bs, xb0, N);
  // layer 2
  k_gemm_mfma<<<GB, 256, 0, stream>>>(xb0, Wt + (size_t)HID * HID, hbuf, N);
  k_aggregate<<<(N + 3) / 4, 256, 0, stream>>>(
      hbuf, row_off, csr4, bs + HID, xb1, N);
  // layer 3
  k_gemm_mfma<<<GB, 256, 0, stream>>>(xb1, Wt + (size_t)2 * HID * HID, hbuf, N);
  k_aggregate<<<(N + 3) / 4, 256, 0, stream>>>(
      hbuf, row_off, csr4, bs + 2 * HID, xb0, N);
  k_classifier<<<(N + 7) / 8, 256, 0, stream>>>(xb0, Wc, bc, out, N);
}

// Round 13
// 313.327 us; speedup vs baseline: 2.1567x; 1.0009x over previous
//
#include <hip/hip_runtime.h>
#include <hip/hip_fp16.h>
#include <math.h>

#define HID 128
#define NCLS 32
#define BCAP 12288   // per-bucket capacity in bins (mean 8704, +38 sigma)
#define SCAP 9728    // LDS sort capacity (mean 8704, +11 sigma)

typedef _Float16 half8 __attribute__((ext_vector_type(8)));
typedef _Float16 h2 __attribute__((ext_vector_type(2)));
typedef float f32x4 __attribute__((ext_vector_type(4)));

union hbits_u { unsigned short u; _Float16 f; };

__device__ __forceinline__ void gload_lds16(const void* g, void* l) {
  __builtin_amdgcn_global_load_lds(
      (const __attribute__((address_space(1))) void*)g,
      (__attribute__((address_space(3))) void*)l, 16, 0, 0);
}

__device__ __forceinline__ h2 pk_max(h2 a, h2 b) {
  return __builtin_elementwise_max(a, b);   // v_pk_max_f16
}

__device__ __forceinline__ _Float16 dec_w(unsigned e) {
  hbits_u u; u.u = (unsigned short)((e >> 16) & 0xFFFEu);
  return u.f;
}

// ---------------------------------------------------------------- prep (Wt + Wct)
__global__ void k_prep_w(const float* __restrict__ Ws, const float* __restrict__ Wc,
                         __half* __restrict__ Wt, float* __restrict__ Wct,
                         int totalW, int totalC) {
  int i = blockIdx.x * blockDim.x + threadIdx.x;
  if (i < totalW) {
    int l = i >> 14, r = i & 16383;
    int nn = r >> 7, k = r & 127;
    Wt[i] = __float2half_rn(Ws[(l << 14) + k * HID + nn]);
  } else if (i < totalW + totalC) {
    int j = i - totalW;
    int c = j >> 7, ch = j & 127;
    Wct[j] = Wc[ch * NCLS + c];
  }
}

// ---------------------------------------------------------------- binned CSR build
__global__ __launch_bounds__(1024) void k_bin(const int* __restrict__ ei,
                                              const float* __restrict__ norm,
                                              int* __restrict__ bucket_cur,
                                              int2* __restrict__ bins,
                                              int E, int T) {
  __shared__ int bcnt[256];
  __shared__ int bbase[256];
  int tid = threadIdx.x;
  if (tid < 256) bcnt[tid] = 0;
  __syncthreads();
  int base = blockIdx.x * 8192;
  int2 ent[8];
  int bk[8];
  #pragma unroll
  for (int i = 0; i < 8; ++i) {
    int e = base + (i << 10) + tid;
    bk[i] = -1;
    if (e < T) {
      int src, dst;
      if (e < E) { src = ei[e]; dst = ei[E + e]; } else { src = dst = e - E; }
      bk[i] = dst >> 9;
      ent[i] = make_int2(src | ((dst & 511) << 17), __float_as_int(norm[e]));
      atomicAdd(&bcnt[bk[i]], 1);
    }
  }
  __syncthreads();
  if (tid < 256) {
    int c = bcnt[tid];
    bbase[tid] = c ? atomicAdd(&bucket_cur[tid], c) : 0;
    bcnt[tid] = 0;
  }
  __syncthreads();
  #pragma unroll
  for (int i = 0; i < 8; ++i) {
    if (bk[i] >= 0) {
      int pos = bbase[bk[i]] + atomicAdd(&bcnt[bk[i]], 1);
      bins[(size_t)bk[i] * BCAP + pos] = ent[i];
    }
  }
}

// per-bucket counting sort by dstLocal; self-scans bucket counts (no k_bscan);
// emits row_off + packed 4B csr entries (src:17 | norm-fp15:15).
__global__ __launch_bounds__(1024) void k_sortbucket(
    const int2* __restrict__ bins, const int* __restrict__ bucket_cur,
    unsigned* __restrict__ csr4, int* __restrict__ row_off,
    int n, int nb, int T) {
  __shared__ unsigned sorted[SCAP];
  __shared__ int scnt[512];
  __shared__ int wsum[8];
  __shared__ int bscan[256];
  int b = blockIdx.x, tid = threadIdx.x;
  // self-scan of 256 bucket counts (inclusive)
  if (tid < 256) bscan[tid] = (tid < nb) ? bucket_cur[tid] : 0;
  __syncthreads();
  for (int d = 1; d < 256; d <<= 1) {
    int t = (tid < 256 && tid >= d) ? bscan[tid - d] : 0;
    __syncthreads();
    if (tid < 256) bscan[tid] += t;
    __syncthreads();
  }
  int cntb = bucket_cur[b];
  int goff = bscan[b] - cntb;
  int cnt = cntb > SCAP ? SCAP : cntb;
  const int2* src = bins + (size_t)b * BCAP;
  int2 myent[10];
  #pragma unroll
  for (int i = 0; i < 10; ++i) {
    int j = tid + (i << 10);
    if (j < cnt) myent[i] = src[j];
  }
  if (tid < 512) scnt[tid] = 0;
  __syncthreads();
  #pragma unroll
  for (int i = 0; i < 10; ++i) {
    int j = tid + (i << 10);
    if (j < cnt) atomicAdd(&scnt[((unsigned)myent[i].x) >> 17], 1);
  }
  __syncthreads();
  int lane = tid & 63, wid = tid >> 6;
  int v = (tid < 512) ? scnt[tid] : 0;
  int incl = v;
  #pragma unroll
  for (int d = 1; d < 64; d <<= 1) {
    int t = __shfl_up(incl, d, 64);
    if (lane >= d) incl += t;
  }
  if (tid < 512 && lane == 63) wsum[wid] = incl;
  __syncthreads();
  if (tid == 0) {
    int s = 0;
    #pragma unroll
    for (int i = 0; i < 8; ++i) { int t = wsum[i]; wsum[i] = s; s += t; }
  }
  __syncthreads();
  int excl = incl - v + ((tid < 512) ? wsum[wid] : 0);
  int node = (b << 9) + tid;
  if (tid < 512 && node < n) row_off[node] = goff + excl;
  if (b == nb - 1 && tid == 0) row_off[n] = T;
  __syncthreads();
  if (tid < 512) scnt[tid] = excl;
  __syncthreads();
  #pragma unroll
  for (int i = 0; i < 10; ++i) {
    int j = tid + (i << 10);
    if (j < cnt) {
      int2 e = myent[i];
      int pos = atomicAdd(&scnt[((unsigned)e.x) >> 17], 1);
      if (pos < SCAP) {
        __half h = __float2half_rn(__int_as_float(e.y));
        unsigned short hb = *(unsigned short*)&h;
        sorted[pos] = (unsigned)(e.x & 0x1FFFF) | ((unsigned)(hb >> 1) << 17);
      }
    }
  }
  __syncthreads();
  for (int j = tid; j < cnt; j += 1024) csr4[goff + j] = sorted[j];
}

// ---------------------------------------------------------------- MFMA GEMM (fp16 input)
__global__ __launch_bounds__(256) void k_gemm_mfma(const __half* __restrict__ X,
                                                   const __half* __restrict__ Wl,
                                                   __half* __restrict__ H, int n) {
  __shared__ char lds[49152];
  char* ldsW = lds;
  char* ldsX = lds + 32768;
  int tid = threadIdx.x, lane = tid & 63, w = tid >> 6;
  int row0 = blockIdx.x * 64;
  int rows = n - row0; if (rows > 64) rows = 64;
  int vbytes = rows << 8;

  #pragma unroll
  for (int it = 0; it < 8; ++it) {
    int d = (w << 13) + (it << 10) + (lane << 4);
    int src = d ^ (((d >> 8) & 7) << 4);
    gload_lds16((const char*)Wl + src, ldsW + (w << 13) + (it << 10));
  }
  #pragma unroll
  for (int it = 0; it < 4; ++it) {
    int d = (w << 12) + (it << 10) + (lane << 4);
    if (d < vbytes) {
      int src = d ^ (((d >> 8) & 7) << 4);
      gload_lds16((const char*)X + ((size_t)row0 << 8) + src,
                  ldsX + (w << 12) + (it << 10));
    }
  }
  __syncthreads();

  int l15 = lane & 15, lhi = lane >> 4;
  half8 a[4];
  #pragma unroll
  for (int s = 0; s < 4; ++s) {
    int m = (w << 4) + l15;
    int d = (m << 8) + (s << 6) + (lhi << 4);
    a[s] = *(const half8*)(ldsX + (d ^ ((m & 7) << 4)));
  }
  __syncthreads();
  f32x4 acc[8] = {};
  #pragma unroll
  for (int s = 0; s < 4; ++s) {
    #pragma unroll
    for (int t = 0; t < 8; ++t) {
      int nn = (t << 4) + l15;
      int d = (nn << 8) + (s << 6) + (lhi << 4);
      half8 b = *(const half8*)(ldsW + (d ^ ((nn & 7) << 4)));
      acc[t] = __builtin_amdgcn_mfma_f32_16x16x32_f16(a[s], b, acc[t], 0, 0, 0);
    }
  }
  #pragma unroll
  for (int t = 0; t < 8; ++t) {
    #pragma unroll
    for (int r = 0; r < 4; ++r) {
      int row = (w << 4) + (lhi << 2) + r;
      int byt = (row << 8) + (t << 5) + (l15 << 1);
      *(__half*)(ldsX + (byt ^ ((row & 7) << 4))) = __float2half_rn(acc[t][r]);
    }
  }
  __syncthreads();
  #pragma unroll
  for (int it = 0; it < 4; ++it) {
    int g = ((it << 8) + tid) << 4;
    if (g < vbytes) {
      uint4 v = *(const uint4*)(ldsX + (g ^ (((g >> 8) & 7) << 4)));
      *(uint4*)((char*)H + ((size_t)row0 << 8) + g) = v;
    }
  }
}

// ---------------------------------------------------------------- MFMA GEMM (fp32 input, layer 1)
__global__ __launch_bounds__(256) void k_gemm_mfma_f32(const float* __restrict__ X,
                                                       const __half* __restrict__ Wl,
                                                       __half* __restrict__ H, int n) {
  __shared__ char lds[65536];
  char* ldsW = lds;
  char* ldsX = lds + 32768;
  int tid = threadIdx.x, lane = tid & 63, w = tid >> 6;
  int row0 = blockIdx.x * 64;
  int rows = n - row0; if (rows > 64) rows = 64;
  int vbytes32 = rows << 9;
  int vbytes = rows << 8;

  #pragma unroll
  for (int it = 0; it < 8; ++it) {
    int d = (w << 13) + (it << 10) + (lane << 4);
    int src = d ^ (((d >> 8) & 7) << 4);
    gload_lds16((const char*)Wl + src, ldsW + (w << 13) + (it << 10));
  }
  #pragma unroll
  for (int it = 0; it < 8; ++it) {
    int d = (w << 13) + (it << 10) + (lane << 4);
    if (d < vbytes32) {
      int src = d ^ (((d >> 9) & 7) << 4);
      gload_lds16((const char*)X + ((size_t)row0 << 9) + src,
                  ldsX + (w << 13) + (it << 10));
    }
  }
  __syncthreads();

  int l15 = lane & 15, lhi = lane >> 4;
  half8 a[4];
  #pragma unroll
  for (int s = 0; s < 4; ++s) {
    int m = (w << 4) + l15;
    int d0 = (m << 9) + (s << 7) + (lhi << 5);
    int x0 = d0 ^ (((d0 >> 9) & 7) << 4);
    int d1 = d0 + 16;
    int x1 = d1 ^ (((d1 >> 9) & 7) << 4);
    float4 lo = *(const float4*)(ldsX + x0);
    float4 hi = *(const float4*)(ldsX + x1);
    half8 af;
    af[0] = (_Float16)lo.x; af[1] = (_Float16)lo.y;
    af[2] = (_Float16)lo.z; af[3] = (_Float16)lo.w;
    af[4] = (_Float16)hi.x; af[5] = (_Float16)hi.y;
    af[6] = (_Float16)hi.z; af[7] = (_Float16)hi.w;
    a[s] = af;
  }
  __syncthreads();
  f32x4 acc[8] = {};
  #pragma unroll
  for (int s = 0; s < 4; ++s) {
    #pragma unroll
    for (int t = 0; t < 8; ++t) {
      int nn = (t << 4) + l15;
      int d = (nn << 8) + (s << 6) + (lhi << 4);
      half8 b = *(const half8*)(ldsW + (d ^ ((nn & 7) << 4)));
      acc[t] = __builtin_amdgcn_mfma_f32_16x16x32_f16(a[s], b, acc[t], 0, 0, 0);
    }
  }
  #pragma unroll
  for (int t = 0; t < 8; ++t) {
    #pragma unroll
    for (int r = 0; r < 4; ++r) {
      int row = (w << 4) + (lhi << 2) + r;
      int byt = (row << 8) + (t << 5) + (l15 << 1);
      *(__half*)(ldsX + (byt ^ ((row & 7) << 4))) = __float2half_rn(acc[t][r]);
    }
  }
  __syncthreads();
  #pragma unroll
  for (int it = 0; it < 4; ++it) {
    int g = ((it << 8) + tid) << 4;
    if (g < vbytes) {
      uint4 v = *(const uint4*)(ldsX + (g ^ (((g >> 8) & 7) << 4)));
      *(uint4*)((char*)H + ((size_t)row0 << 8) + g) = v;
    }
  }
}

// ---------------------------------------------------------------- aggregate gather core
#define AGG_GATHER                                                             \
  int lane = threadIdx.x & 63;                                                 \
  int q = lane >> 4, l4 = lane & 15;                                           \
  int beg = row_off[node], end = row_off[node + 1];                            \
  const char* Hb = (const char*)H + (l4 << 4);                                 \
  const unsigned NEG = 0xFC00FC00u;                                            \
  h2 m0 = *(const h2*)&NEG, m1 = m0, m2 = m0, m3 = m0;                         \
  int j = beg + q;                                                             \
  for (; j + 12 < end; j += 16) {                                              \
    unsigned e0 = csr4[j], e1 = csr4[j + 4], e2 = csr4[j + 8], e3 = csr4[j + 12]; \
    _Float16 w0 = dec_w(e0), w1 = dec_w(e1), w2 = dec_w(e2), w3 = dec_w(e3);   \
    uint4 r0 = *(const uint4*)(Hb + ((size_t)(e0 & 0x1FFFF) << 8));            \
    uint4 r1 = *(const uint4*)(Hb + ((size_t)(e1 & 0x1FFFF) << 8));            \
    uint4 r2 = *(const uint4*)(Hb + ((size_t)(e2 & 0x1FFFF) << 8));            \
    uint4 r3 = *(const uint4*)(Hb + ((size_t)(e3 & 0x1FFFF) << 8));            \
    m0 = pk_max(m0, *(h2*)&r0.x * w0);                                         \
    m1 = pk_max(m1, *(h2*)&r0.y * w0);                                         \
    m2 = pk_max(m2, *(h2*)&r0.z * w0);                                         \
    m3 = pk_max(m3, *(h2*)&r0.w * w0);                                         \
    m0 = pk_max(m0, *(h2*)&r1.x * w1);                                         \
    m1 = pk_max(m1, *(h2*)&r1.y * w1);                                         \
    m2 = pk_max(m2, *(h2*)&r1.z * w1);                                         \
    m3 = pk_max(m3, *(h2*)&r1.w * w1);                                         \
    m0 = pk_max(m0, *(h2*)&r2.x * w2);                                         \
    m1 = pk_max(m1, *(h2*)&r2.y * w2);                                         \
    m2 = pk_max(m2, *(h2*)&r2.z * w2);                                         \
    m3 = pk_max(m3, *(h2*)&r2.w * w2);                                         \
    m0 = pk_max(m0, *(h2*)&r3.x * w3);                                         \
    m1 = pk_max(m1, *(h2*)&r3.y * w3);                                         \
    m2 = pk_max(m2, *(h2*)&r3.z * w3);                                         \
    m3 = pk_max(m3, *(h2*)&r3.w * w3);                                         \
  }                                                                            \
  for (; j < end; j += 4) {                                                    \
    unsigned e0 = csr4[j];                                                     \
    _Float16 w0 = dec_w(e0);                                                   \
    uint4 r0 = *(const uint4*)(Hb + ((size_t)(e0 & 0x1FFFF) << 8));            \
    m0 = pk_max(m0, *(h2*)&r0.x * w0);                                         \
    m1 = pk_max(m1, *(h2*)&r0.y * w0);                                         \
    m2 = pk_max(m2, *(h2*)&r0.z * w0);                                         \
    m3 = pk_max(m3, *(h2*)&r0.w * w0);                                         \
  }                                                                            \
  _Pragma("unroll")                                                            \
  for (int d = 16; d <= 32; d <<= 1) {                                         \
    unsigned u0 = __shfl_xor(*(unsigned*)&m0, d, 64);                          \
    unsigned u1 = __shfl_xor(*(unsigned*)&m1, d, 64);                          \
    unsigned u2 = __shfl_xor(*(unsigned*)&m2, d, 64);                          \
    unsigned u3 = __shfl_xor(*(unsigned*)&m3, d, 64);                          \
    m0 = pk_max(m0, *(h2*)&u0);                                                \
    m1 = pk_max(m1, *(h2*)&u1);                                                \
    m2 = pk_max(m2, *(h2*)&u2);                                                \
    m3 = pk_max(m3, *(h2*)&u3);                                                \
  }

// ---------------------------------------------------------------- aggregate (mid layers)
__global__ __launch_bounds__(256) void k_aggregate(
    const __half* __restrict__ H, const int* __restrict__ row_off,
    const unsigned* __restrict__ csr4, const float* __restrict__ bias,
    __half* __restrict__ Xout, int n) {
  int node = (int)((blockIdx.x * blockDim.x + threadIdx.x) >> 6);
  if (node >= n) return;
  AGG_GATHER
  if (q == 0) {
    float f0x = (float)m0.x, f0y = (float)m0.y;
    float f1x = (float)m1.x, f1y = (float)m1.y;
    float f2x = (float)m2.x, f2y = (float)m2.y;
    float f3x = (float)m3.x, f3y = (float)m3.y;
    if (end == beg) { f0x=f0y=f1x=f1y=f2x=f2y=f3x=f3y = 0.f; }
    float4 b0 = ((const float4*)bias)[l4 << 1];
    float4 b1 = ((const float4*)bias)[(l4 << 1) + 1];
    __half2 o0 = __floats2half2_rn(fmaxf(f0x + b0.x, 0.f), fmaxf(f0y + b0.y, 0.f));
    __half2 o1 = __floats2half2_rn(fmaxf(f1x + b0.z, 0.f), fmaxf(f1y + b0.w, 0.f));
    __half2 o2 = __floats2half2_rn(fmaxf(f2x + b1.x, 0.f), fmaxf(f2y + b1.y, 0.f));
    __half2 o3 = __floats2half2_rn(fmaxf(f3x + b1.z, 0.f), fmaxf(f3y + b1.w, 0.f));
    uint4 ov = make_uint4(*(unsigned*)&o0, *(unsigned*)&o1,
                          *(unsigned*)&o2, *(unsigned*)&o3);
    *(uint4*)((char*)Xout + ((size_t)node << 8) + (l4 << 4)) = ov;
  }
}

// ---------------------------------------------------------------- aggregate + classifier (layer 3)
// after quarter-merge every lane holds its 8 channels of final x in regs;
// quarter q computes classes [8q,8q+8): 64 fma/lane vs Wct (L2-hot), butterfly
// over 16 lanes, 32-class log_softmax via 2 cross-quarter shuffles.
__global__ __launch_bounds__(256) void k_aggregate_cls(
    const __half* __restrict__ H, const int* __restrict__ row_off,
    const unsigned* __restrict__ csr4, const float* __restrict__ bias,
    const float* __restrict__ Wct, const float* __restrict__ bc,
    float* __restrict__ out, int n) {
  int node = (int)((blockIdx.x * blockDim.x + threadIdx.x) >> 6);
  if (node >= n) return;
  AGG_GATHER
  // x channels l4*8 .. l4*8+7, relu(val+bias) in fp32
  float xv[8];
  xv[0] = (float)m0.x; xv[1] = (float)m0.y;
  xv[2] = (float)m1.x; xv[3] = (float)m1.y;
  xv[4] = (float)m2.x; xv[5] = (float)m2.y;
  xv[6] = (float)m3.x; xv[7] = (float)m3.y;
  if (end == beg) {
    #pragma unroll
    for (int k = 0; k < 8; ++k) xv[k] = 0.f;
  }
  {
    float4 b0 = ((const float4*)bias)[l4 << 1];
    float4 b1 = ((const float4*)bias)[(l4 << 1) + 1];
    xv[0] = fmaxf(xv[0] + b0.x, 0.f); xv[1] = fmaxf(xv[1] + b0.y, 0.f);
    xv[2] = fmaxf(xv[2] + b0.z, 0.f); xv[3] = fmaxf(xv[3] + b0.w, 0.f);
    xv[4] = fmaxf(xv[4] + b1.x, 0.f); xv[5] = fmaxf(xv[5] + b1.y, 0.f);
    xv[6] = fmaxf(xv[6] + b1.z, 0.f); xv[7] = fmaxf(xv[7] + b1.w, 0.f);
  }
  // logits for classes c = 8q+t
  float lg[8];
  #pragma unroll
  for (int t = 0; t < 8; ++t) {
    const float4* wp = (const float4*)(Wct + (((q << 3) + t) << 7) + (l4 << 3));
    float4 wa = wp[0], wb = wp[1];
    float s = xv[0] * wa.x + xv[1] * wa.y + xv[2] * wa.z + xv[3] * wa.w;
    s += xv[4] * wb.x + xv[5] * wb.y + xv[6] * wb.z + xv[7] * wb.w;
    lg[t] = s;
  }
  #pragma unroll
  for (int d = 1; d <= 8; d <<= 1) {
    #pragma unroll
    for (int t = 0; t < 8; ++t) lg[t] += __shfl_xor(lg[t], d, 64);
  }
  #pragma unroll
  for (int t = 0; t < 8; ++t) lg[t] += bc[(q << 3) + t];
  // log_softmax over 32 classes
  float mx = lg[0];
  #pragma unroll
  for (int t = 1; t < 8; ++t) mx = fmaxf(mx, lg[t]);
  mx = fmaxf(mx, __shfl_xor(mx, 16, 64));
  mx = fmaxf(mx, __shfl_xor(mx, 32, 64));
  float se = 0.f;
  #pragma unroll
  for (int t = 0; t < 8; ++t) se += expf(lg[t] - mx);
  se += __shfl_xor(se, 16, 64);
  se += __shfl_xor(se, 32, 64);
  float ls = logf(se) + mx;
  if (l4 == 0) {
    float* dst = out + (size_t)node * NCLS + (q << 3);
    *(float4*)dst = make_float4(lg[0] - ls, lg[1] - ls, lg[2] - ls, lg[3] - ls);
    *(float4*)(dst + 4) = make_float4(lg[4] - ls, lg[5] - ls, lg[6] - ls, lg[7] - ls);
  }
}

// ---------------------------------------------------------------- launch
extern "C" void kernel_launch(void* const* d_in, const int* in_sizes, int n_in,
                              void* d_out, int out_size, void* d_ws, size_t ws_size,
                              hipStream_t stream) {
  const float* x    = (const float*)d_in[0];
  const int*   ei   = (const int*)d_in[1];
  const float* norm = (const float*)d_in[2];
  const float* Ws   = (const float*)d_in[3];
  const float* bs   = (const float*)d_in[4];
  const float* Wc   = (const float*)d_in[5];
  const float* bc   = (const float*)d_in[6];
  float* out = (float*)d_out;

  const int N = in_sizes[0] / HID;
  const int E = in_sizes[1] / 2;
  const int L = in_sizes[3] / (HID * HID);
  const int T = E + N;
  const int NB = (N + 511) >> 9;

  char* p = (char*)d_ws;
  auto alloc = [&](size_t bytes) {
    char* r = p; p += (bytes + 255) & ~(size_t)255; return r;
  };
  __half*   xb0        = (__half*)alloc((size_t)N * HID * 2);
  __half*   xb1        = (__half*)alloc((size_t)N * HID * 2);
  __half*   hbuf       = (__half*)alloc((size_t)N * HID * 2);
  __half*   Wt         = (__half*)alloc((size_t)L * HID * HID * 2);
  float*    Wct        = (float*)alloc((size_t)HID * NCLS * 4);
  int*      row_off    = (int*)alloc(((size_t)N + 1) * 4);
  int*      bucket_cur = (int*)alloc(256 * 4);
  int2*     bins       = (int2*)alloc((size_t)NB * BCAP * 8);
  unsigned* csr4       = (unsigned*)alloc((size_t)T * 4);
  (void)ws_size; (void)n_in; (void)out_size;

  const int totalW = L * HID * HID;
  const int totalC = HID * NCLS;
  hipMemsetAsync(bucket_cur, 0, 256 * 4, stream);
  k_prep_w<<<(totalW + totalC + 255) / 256, 256, 0, stream>>>(
      Ws, Wc, Wt, Wct, totalW, totalC);
  k_bin<<<(T + 8191) / 8192, 1024, 0, stream>>>(ei, norm, bucket_cur, bins, E, T);
  k_sortbucket<<<NB, 1024, 0, stream>>>(bins, bucket_cur, csr4, row_off, N, NB, T);

  const int GB = (N + 63) / 64;
  k_gemm_mfma_f32<<<GB, 256, 0, stream>>>(x, Wt, hbuf, N);
  k_aggregate<<<(N + 3) / 4, 256, 0, stream>>>(hbuf, row_off, csr4, bs, xb0, N);
  k_gemm_mfma<<<GB, 256, 0, stream>>>(xb0, Wt + (size_t)HID * HID, hbuf, N);
  k_aggregate<<<(N + 3) / 4, 256, 0, stream>>>(hbuf, row_off, csr4, bs + HID, xb1, N);
  k_gemm_mfma<<<GB, 256, 0, stream>>>(xb1, Wt + (size_t)2 * HID * HID, hbuf, N);
  k_aggregate_cls<<<(N + 3) / 4, 256, 0, stream>>>(
      hbuf, row_off, csr4, bs + 2 * HID, Wct, bc, out, N);
}

// Round 14
// 276.236 us; speedup vs baseline: 2.4463x; 1.1343x over previous
//
#include <hip/hip_runtime.h>
#include <hip/hip_fp16.h>
#include <math.h>

#define HID 128
#define NCLS 32
#define BCAP 12288   // per-bucket capacity in bins (mean 8704, +38 sigma)
#define SCAP 9728    // LDS sort capacity (mean 8704, +11 sigma)

typedef _Float16 half8 __attribute__((ext_vector_type(8)));
typedef _Float16 h2 __attribute__((ext_vector_type(2)));
typedef float f32x4 __attribute__((ext_vector_type(4)));

union hbits_u { unsigned short u; _Float16 f; };

__device__ __forceinline__ void gload_lds16(const void* g, void* l) {
  __builtin_amdgcn_global_load_lds(
      (const __attribute__((address_space(1))) void*)g,
      (__attribute__((address_space(3))) void*)l, 16, 0, 0);
}

__device__ __forceinline__ h2 pk_max(h2 a, h2 b) {
  return __builtin_elementwise_max(a, b);   // v_pk_max_f16
}

__device__ __forceinline__ _Float16 dec_w(unsigned e) {
  hbits_u u; u.u = (unsigned short)((e >> 16) & 0xFFFEu);
  return u.f;
}

// ---------------------------------------------------------------- prep (Wt + Wch)
// Wt[l][n][k] fp16; Wch[c][k] fp16 (classifier weights transposed)
__global__ void k_prep_w(const float* __restrict__ Ws, const float* __restrict__ Wc,
                         __half* __restrict__ Wt, __half* __restrict__ Wch,
                         int totalW, int totalC) {
  int i = blockIdx.x * blockDim.x + threadIdx.x;
  if (i < totalW) {
    int l = i >> 14, r = i & 16383;
    int nn = r >> 7, k = r & 127;
    Wt[i] = __float2half_rn(Ws[(l << 14) + k * HID + nn]);
  } else if (i < totalW + totalC) {
    int j = i - totalW;
    int c = j >> 7, k = j & 127;
    Wch[j] = __float2half_rn(Wc[k * NCLS + c]);
  }
}

// ---------------------------------------------------------------- binned CSR build
__global__ __launch_bounds__(1024) void k_bin(const int* __restrict__ ei,
                                              const float* __restrict__ norm,
                                              int* __restrict__ bucket_cur,
                                              int2* __restrict__ bins,
                                              int E, int T) {
  __shared__ int bcnt[256];
  __shared__ int bbase[256];
  int tid = threadIdx.x;
  if (tid < 256) bcnt[tid] = 0;
  __syncthreads();
  int base = blockIdx.x * 8192;
  int2 ent[8];
  int bk[8];
  #pragma unroll
  for (int i = 0; i < 8; ++i) {
    int e = base + (i << 10) + tid;
    bk[i] = -1;
    if (e < T) {
      int src, dst;
      if (e < E) { src = ei[e]; dst = ei[E + e]; } else { src = dst = e - E; }
      bk[i] = dst >> 9;
      ent[i] = make_int2(src | ((dst & 511) << 17), __float_as_int(norm[e]));
      atomicAdd(&bcnt[bk[i]], 1);
    }
  }
  __syncthreads();
  if (tid < 256) {
    int c = bcnt[tid];
    bbase[tid] = c ? atomicAdd(&bucket_cur[tid], c) : 0;
    bcnt[tid] = 0;
  }
  __syncthreads();
  #pragma unroll
  for (int i = 0; i < 8; ++i) {
    if (bk[i] >= 0) {
      int pos = bbase[bk[i]] + atomicAdd(&bcnt[bk[i]], 1);
      bins[(size_t)bk[i] * BCAP + pos] = ent[i];
    }
  }
}

// per-bucket counting sort by dstLocal; self-scans bucket counts;
// emits row_off + packed 4B csr entries (src:17 | norm-fp15:15).
__global__ __launch_bounds__(1024) void k_sortbucket(
    const int2* __restrict__ bins, const int* __restrict__ bucket_cur,
    unsigned* __restrict__ csr4, int* __restrict__ row_off,
    int n, int nb, int T) {
  __shared__ unsigned sorted[SCAP];
  __shared__ int scnt[512];
  __shared__ int wsum[8];
  __shared__ int bscan[256];
  int b = blockIdx.x, tid = threadIdx.x;
  if (tid < 256) bscan[tid] = (tid < nb) ? bucket_cur[tid] : 0;
  __syncthreads();
  for (int d = 1; d < 256; d <<= 1) {
    int t = (tid < 256 && tid >= d) ? bscan[tid - d] : 0;
    __syncthreads();
    if (tid < 256) bscan[tid] += t;
    __syncthreads();
  }
  int cntb = bucket_cur[b];
  int goff = bscan[b] - cntb;
  int cnt = cntb > SCAP ? SCAP : cntb;
  const int2* src = bins + (size_t)b * BCAP;
  int2 myent[10];
  #pragma unroll
  for (int i = 0; i < 10; ++i) {
    int j = tid + (i << 10);
    if (j < cnt) myent[i] = src[j];
  }
  if (tid < 512) scnt[tid] = 0;
  __syncthreads();
  #pragma unroll
  for (int i = 0; i < 10; ++i) {
    int j = tid + (i << 10);
    if (j < cnt) atomicAdd(&scnt[((unsigned)myent[i].x) >> 17], 1);
  }
  __syncthreads();
  int lane = tid & 63, wid = tid >> 6;
  int v = (tid < 512) ? scnt[tid] : 0;
  int incl = v;
  #pragma unroll
  for (int d = 1; d < 64; d <<= 1) {
    int t = __shfl_up(incl, d, 64);
    if (lane >= d) incl += t;
  }
  if (tid < 512 && lane == 63) wsum[wid] = incl;
  __syncthreads();
  if (tid == 0) {
    int s = 0;
    #pragma unroll
    for (int i = 0; i < 8; ++i) { int t = wsum[i]; wsum[i] = s; s += t; }
  }
  __syncthreads();
  int excl = incl - v + ((tid < 512) ? wsum[wid] : 0);
  int node = (b << 9) + tid;
  if (tid < 512 && node < n) row_off[node] = goff + excl;
  if (b == nb - 1 && tid == 0) row_off[n] = T;
  __syncthreads();
  if (tid < 512) scnt[tid] = excl;
  __syncthreads();
  #pragma unroll
  for (int i = 0; i < 10; ++i) {
    int j = tid + (i << 10);
    if (j < cnt) {
      int2 e = myent[i];
      int pos = atomicAdd(&scnt[((unsigned)e.x) >> 17], 1);
      if (pos < SCAP) {
        __half h = __float2half_rn(__int_as_float(e.y));
        unsigned short hb = *(unsigned short*)&h;
        sorted[pos] = (unsigned)(e.x & 0x1FFFF) | ((unsigned)(hb >> 1) << 17);
      }
    }
  }
  __syncthreads();
  for (int j = tid; j < cnt; j += 1024) csr4[goff + j] = sorted[j];
}

// ---------------------------------------------------------------- MFMA GEMM (fp16 input)
__global__ __launch_bounds__(256) void k_gemm_mfma(const __half* __restrict__ X,
                                                   const __half* __restrict__ Wl,
                                                   __half* __restrict__ H, int n) {
  __shared__ char lds[49152];
  char* ldsW = lds;
  char* ldsX = lds + 32768;
  int tid = threadIdx.x, lane = tid & 63, w = tid >> 6;
  int row0 = blockIdx.x * 64;
  int rows = n - row0; if (rows > 64) rows = 64;
  int vbytes = rows << 8;

  #pragma unroll
  for (int it = 0; it < 8; ++it) {
    int d = (w << 13) + (it << 10) + (lane << 4);
    int src = d ^ (((d >> 8) & 7) << 4);
    gload_lds16((const char*)Wl + src, ldsW + (w << 13) + (it << 10));
  }
  #pragma unroll
  for (int it = 0; it < 4; ++it) {
    int d = (w << 12) + (it << 10) + (lane << 4);
    if (d < vbytes) {
      int src = d ^ (((d >> 8) & 7) << 4);
      gload_lds16((const char*)X + ((size_t)row0 << 8) + src,
                  ldsX + (w << 12) + (it << 10));
    }
  }
  __syncthreads();

  int l15 = lane & 15, lhi = lane >> 4;
  half8 a[4];
  #pragma unroll
  for (int s = 0; s < 4; ++s) {
    int m = (w << 4) + l15;
    int d = (m << 8) + (s << 6) + (lhi << 4);
    a[s] = *(const half8*)(ldsX + (d ^ ((m & 7) << 4)));
  }
  __syncthreads();
  f32x4 acc[8] = {};
  #pragma unroll
  for (int s = 0; s < 4; ++s) {
    #pragma unroll
    for (int t = 0; t < 8; ++t) {
      int nn = (t << 4) + l15;
      int d = (nn << 8) + (s << 6) + (lhi << 4);
      half8 b = *(const half8*)(ldsW + (d ^ ((nn & 7) << 4)));
      acc[t] = __builtin_amdgcn_mfma_f32_16x16x32_f16(a[s], b, acc[t], 0, 0, 0);
    }
  }
  #pragma unroll
  for (int t = 0; t < 8; ++t) {
    #pragma unroll
    for (int r = 0; r < 4; ++r) {
      int row = (w << 4) + (lhi << 2) + r;
      int byt = (row << 8) + (t << 5) + (l15 << 1);
      *(__half*)(ldsX + (byt ^ ((row & 7) << 4))) = __float2half_rn(acc[t][r]);
    }
  }
  __syncthreads();
  #pragma unroll
  for (int it = 0; it < 4; ++it) {
    int g = ((it << 8) + tid) << 4;
    if (g < vbytes) {
      uint4 v = *(const uint4*)(ldsX + (g ^ (((g >> 8) & 7) << 4)));
      *(uint4*)((char*)H + ((size_t)row0 << 8) + g) = v;
    }
  }
}

// ---------------------------------------------------------------- MFMA GEMM (fp32 input, layer 1)
__global__ __launch_bounds__(256) void k_gemm_mfma_f32(const float* __restrict__ X,
                                                       const __half* __restrict__ Wl,
                                                       __half* __restrict__ H, int n) {
  __shared__ char lds[65536];
  char* ldsW = lds;
  char* ldsX = lds + 32768;
  int tid = threadIdx.x, lane = tid & 63, w = tid >> 6;
  int row0 = blockIdx.x * 64;
  int rows = n - row0; if (rows > 64) rows = 64;
  int vbytes32 = rows << 9;
  int vbytes = rows << 8;

  #pragma unroll
  for (int it = 0; it < 8; ++it) {
    int d = (w << 13) + (it << 10) + (lane << 4);
    int src = d ^ (((d >> 8) & 7) << 4);
    gload_lds16((const char*)Wl + src, ldsW + (w << 13) + (it << 10));
  }
  #pragma unroll
  for (int it = 0; it < 8; ++it) {
    int d = (w << 13) + (it << 10) + (lane << 4);
    if (d < vbytes32) {
      int src = d ^ (((d >> 9) & 7) << 4);
      gload_lds16((const char*)X + ((size_t)row0 << 9) + src,
                  ldsX + (w << 13) + (it << 10));
    }
  }
  __syncthreads();

  int l15 = lane & 15, lhi = lane >> 4;
  half8 a[4];
  #pragma unroll
  for (int s = 0; s < 4; ++s) {
    int m = (w << 4) + l15;
    int d0 = (m << 9) + (s << 7) + (lhi << 5);
    int x0 = d0 ^ (((d0 >> 9) & 7) << 4);
    int d1 = d0 + 16;
    int x1 = d1 ^ (((d1 >> 9) & 7) << 4);
    float4 lo = *(const float4*)(ldsX + x0);
    float4 hi = *(const float4*)(ldsX + x1);
    half8 af;
    af[0] = (_Float16)lo.x; af[1] = (_Float16)lo.y;
    af[2] = (_Float16)lo.z; af[3] = (_Float16)lo.w;
    af[4] = (_Float16)hi.x; af[5] = (_Float16)hi.y;
    af[6] = (_Float16)hi.z; af[7] = (_Float16)hi.w;
    a[s] = af;
  }
  __syncthreads();
  f32x4 acc[8] = {};
  #pragma unroll
  for (int s = 0; s < 4; ++s) {
    #pragma unroll
    for (int t = 0; t < 8; ++t) {
      int nn = (t << 4) + l15;
      int d = (nn << 8) + (s << 6) + (lhi << 4);
      half8 b = *(const half8*)(ldsW + (d ^ ((nn & 7) << 4)));
      acc[t] = __builtin_amdgcn_mfma_f32_16x16x32_f16(a[s], b, acc[t], 0, 0, 0);
    }
  }
  #pragma unroll
  for (int t = 0; t < 8; ++t) {
    #pragma unroll
    for (int r = 0; r < 4; ++r) {
      int row = (w << 4) + (lhi << 2) + r;
      int byt = (row << 8) + (t << 5) + (l15 << 1);
      *(__half*)(ldsX + (byt ^ ((row & 7) << 4))) = __float2half_rn(acc[t][r]);
    }
  }
  __syncthreads();
  #pragma unroll
  for (int it = 0; it < 4; ++it) {
    int g = ((it << 8) + tid) << 4;
    if (g < vbytes) {
      uint4 v = *(const uint4*)(ldsX + (g ^ (((g >> 8) & 7) << 4)));
      *(uint4*)((char*)H + ((size_t)row0 << 8) + g) = v;
    }
  }
}

// ---------------------------------------------------------------- aggregate
// wave per node, quarter-wave x 16B per edge, 16 edges in flight, packed fp16.
__global__ __launch_bounds__(256) void k_aggregate(
    const __half* __restrict__ H, const int* __restrict__ row_off,
    const unsigned* __restrict__ csr4, const float* __restrict__ bias,
    __half* __restrict__ Xout, int n) {
  int node = (int)((blockIdx.x * blockDim.x + threadIdx.x) >> 6);
  if (node >= n) return;
  int lane = threadIdx.x & 63;
  int q = lane >> 4, l4 = lane & 15;
  int beg = row_off[node], end = row_off[node + 1];
  const char* Hb = (const char*)H + (l4 << 4);
  const unsigned NEG = 0xFC00FC00u;
  h2 m0 = *(const h2*)&NEG, m1 = m0, m2 = m0, m3 = m0;
  int j = beg + q;
  for (; j + 12 < end; j += 16) {
    unsigned e0 = csr4[j], e1 = csr4[j + 4], e2 = csr4[j + 8], e3 = csr4[j + 12];
    _Float16 w0 = dec_w(e0), w1 = dec_w(e1), w2 = dec_w(e2), w3 = dec_w(e3);
    uint4 r0 = *(const uint4*)(Hb + ((size_t)(e0 & 0x1FFFF) << 8));
    uint4 r1 = *(const uint4*)(Hb + ((size_t)(e1 & 0x1FFFF) << 8));
    uint4 r2 = *(const uint4*)(Hb + ((size_t)(e2 & 0x1FFFF) << 8));
    uint4 r3 = *(const uint4*)(Hb + ((size_t)(e3 & 0x1FFFF) << 8));
    m0 = pk_max(m0, *(h2*)&r0.x * w0);
    m1 = pk_max(m1, *(h2*)&r0.y * w0);
    m2 = pk_max(m2, *(h2*)&r0.z * w0);
    m3 = pk_max(m3, *(h2*)&r0.w * w0);
    m0 = pk_max(m0, *(h2*)&r1.x * w1);
    m1 = pk_max(m1, *(h2*)&r1.y * w1);
    m2 = pk_max(m2, *(h2*)&r1.z * w1);
    m3 = pk_max(m3, *(h2*)&r1.w * w1);
    m0 = pk_max(m0, *(h2*)&r2.x * w2);
    m1 = pk_max(m1, *(h2*)&r2.y * w2);
    m2 = pk_max(m2, *(h2*)&r2.z * w2);
    m3 = pk_max(m3, *(h2*)&r2.w * w2);
    m0 = pk_max(m0, *(h2*)&r3.x * w3);
    m1 = pk_max(m1, *(h2*)&r3.y * w3);
    m2 = pk_max(m2, *(h2*)&r3.z * w3);
    m3 = pk_max(m3, *(h2*)&r3.w * w3);
  }
  for (; j < end; j += 4) {
    unsigned e0 = csr4[j];
    _Float16 w0 = dec_w(e0);
    uint4 r0 = *(const uint4*)(Hb + ((size_t)(e0 & 0x1FFFF) << 8));
    m0 = pk_max(m0, *(h2*)&r0.x * w0);
    m1 = pk_max(m1, *(h2*)&r0.y * w0);
    m2 = pk_max(m2, *(h2*)&r0.z * w0);
    m3 = pk_max(m3, *(h2*)&r0.w * w0);
  }
  #pragma unroll
  for (int d = 16; d <= 32; d <<= 1) {
    unsigned u0 = __shfl_xor(*(unsigned*)&m0, d, 64);
    unsigned u1 = __shfl_xor(*(unsigned*)&m1, d, 64);
    unsigned u2 = __shfl_xor(*(unsigned*)&m2, d, 64);
    unsigned u3 = __shfl_xor(*(unsigned*)&m3, d, 64);
    m0 = pk_max(m0, *(h2*)&u0);
    m1 = pk_max(m1, *(h2*)&u1);
    m2 = pk_max(m2, *(h2*)&u2);
    m3 = pk_max(m3, *(h2*)&u3);
  }
  if (q == 0) {
    float f0x = (float)m0.x, f0y = (float)m0.y;
    float f1x = (float)m1.x, f1y = (float)m1.y;
    float f2x = (float)m2.x, f2y = (float)m2.y;
    float f3x = (float)m3.x, f3y = (float)m3.y;
    if (end == beg) { f0x=f0y=f1x=f1y=f2x=f2y=f3x=f3y = 0.f; }
    float4 b0 = ((const float4*)bias)[l4 << 1];
    float4 b1 = ((const float4*)bias)[(l4 << 1) + 1];
    __half2 o0 = __floats2half2_rn(fmaxf(f0x + b0.x, 0.f), fmaxf(f0y + b0.y, 0.f));
    __half2 o1 = __floats2half2_rn(fmaxf(f1x + b0.z, 0.f), fmaxf(f1y + b0.w, 0.f));
    __half2 o2 = __floats2half2_rn(fmaxf(f2x + b1.x, 0.f), fmaxf(f2y + b1.y, 0.f));
    __half2 o3 = __floats2half2_rn(fmaxf(f3x + b1.z, 0.f), fmaxf(f3y + b1.w, 0.f));
    uint4 ov = make_uint4(*(unsigned*)&o0, *(unsigned*)&o1,
                          *(unsigned*)&o2, *(unsigned*)&o3);
    *(uint4*)((char*)Xout + ((size_t)node << 8) + (l4 << 4)) = ov;
  }
}

// ---------------------------------------------------------------- classifier (MFMA) + log_softmax
// 64 nodes/block; Wch fp16 [32][128] (8KB) + X tile (16KB) in LDS; 8 MFMAs;
// each 16-lane group holds one row's 32 logits -> 4-round butterfly softmax.
__global__ __launch_bounds__(256) void k_classifier_mfma(
    const __half* __restrict__ X, const __half* __restrict__ Wch,
    const float* __restrict__ bc, float* __restrict__ out, int n) {
  __shared__ char lds[24576];
  char* ldsW = lds;           // 8KB
  char* ldsX = lds + 8192;    // 16KB
  int tid = threadIdx.x, lane = tid & 63, w = tid >> 6;
  int row0 = blockIdx.x * 64;
  int rows = n - row0; if (rows > 64) rows = 64;
  int vbytes = rows << 8;
  #pragma unroll
  for (int it = 0; it < 2; ++it) {
    int d = (it << 12) + (w << 10) + (lane << 4);
    int src = d ^ (((d >> 8) & 7) << 4);
    gload_lds16((const char*)Wch + src, ldsW + (it << 12) + (w << 10));
  }
  #pragma unroll
  for (int it = 0; it < 4; ++it) {
    int d = (w << 12) + (it << 10) + (lane << 4);
    if (d < vbytes) {
      int src = d ^ (((d >> 8) & 7) << 4);
      gload_lds16((const char*)X + ((size_t)row0 << 8) + src,
                  ldsX + (w << 12) + (it << 10));
    }
  }
  __syncthreads();
  int l15 = lane & 15, lhi = lane >> 4;
  f32x4 acc[2] = {};
  #pragma unroll
  for (int s = 0; s < 4; ++s) {
    int m = (w << 4) + l15;
    int d = (m << 8) + (s << 6) + (lhi << 4);
    half8 a = *(const half8*)(ldsX + (d ^ ((m & 7) << 4)));
    #pragma unroll
    for (int t = 0; t < 2; ++t) {
      int nn = (t << 4) + l15;
      int dw = (nn << 8) + (s << 6) + (lhi << 4);
      half8 b = *(const half8*)(ldsW + (dw ^ ((nn & 7) << 4)));
      acc[t] = __builtin_amdgcn_mfma_f32_16x16x32_f16(a, b, acc[t], 0, 0, 0);
    }
  }
  float bc0 = bc[l15], bc1 = bc[l15 + 16];
  #pragma unroll
  for (int r = 0; r < 4; ++r) {
    int row = (w << 4) + (lhi << 2) + r;
    float lg0 = acc[0][r] + bc0;
    float lg1 = acc[1][r] + bc1;
    float mx = fmaxf(lg0, lg1);
    #pragma unroll
    for (int d = 1; d <= 8; d <<= 1) mx = fmaxf(mx, __shfl_xor(mx, d, 64));
    float se = expf(lg0 - mx) + expf(lg1 - mx);
    #pragma unroll
    for (int d = 1; d <= 8; d <<= 1) se += __shfl_xor(se, d, 64);
    float ls = logf(se) + mx;
    int gnode = row0 + row;
    if (gnode < n) {
      out[(size_t)gnode * NCLS + l15] = lg0 - ls;
      out[(size_t)gnode * NCLS + l15 + 16] = lg1 - ls;
    }
  }
}

// ---------------------------------------------------------------- launch
extern "C" void kernel_launch(void* const* d_in, const int* in_sizes, int n_in,
                              void* d_out, int out_size, void* d_ws, size_t ws_size,
                              hipStream_t stream) {
  const float* x    = (const float*)d_in[0];
  const int*   ei   = (const int*)d_in[1];
  const float* norm = (const float*)d_in[2];
  const float* Ws   = (const float*)d_in[3];
  const float* bs   = (const float*)d_in[4];
  const float* Wc   = (const float*)d_in[5];
  const float* bc   = (const float*)d_in[6];
  float* out = (float*)d_out;

  const int N = in_sizes[0] / HID;
  const int E = in_sizes[1] / 2;
  const int L = in_sizes[3] / (HID * HID);
  const int T = E + N;
  const int NB = (N + 511) >> 9;

  char* p = (char*)d_ws;
  auto alloc = [&](size_t bytes) {
    char* r = p; p += (bytes + 255) & ~(size_t)255; return r;
  };
  __half*   xb0        = (__half*)alloc((size_t)N * HID * 2);
  __half*   xb1        = (__half*)alloc((size_t)N * HID * 2);
  __half*   hbuf       = (__half*)alloc((size_t)N * HID * 2);
  __half*   Wt         = (__half*)alloc((size_t)L * HID * HID * 2);
  __half*   Wch        = (__half*)alloc((size_t)HID * NCLS * 2);
  int*      row_off    = (int*)alloc(((size_t)N + 1) * 4);
  int*      bucket_cur = (int*)alloc(256 * 4);
  int2*     bins       = (int2*)alloc((size_t)NB * BCAP * 8);
  unsigned* csr4       = (unsigned*)alloc((size_t)T * 4);
  (void)ws_size; (void)n_in; (void)out_size;

  const int totalW = L * HID * HID;
  const int totalC = HID * NCLS;
  hipMemsetAsync(bucket_cur, 0, 256 * 4, stream);
  k_prep_w<<<(totalW + totalC + 255) / 256, 256, 0, stream>>>(
      Ws, Wc, Wt, Wch, totalW, totalC);
  k_bin<<<(T + 8191) / 8192, 1024, 0, stream>>>(ei, norm, bucket_cur, bins, E, T);
  k_sortbucket<<<NB, 1024, 0, stream>>>(bins, bucket_cur, csr4, row_off, N, NB, T);

  const int GB = (N + 63) / 64;
  k_gemm_mfma_f32<<<GB, 256, 0, stream>>>(x, Wt, hbuf, N);
  k_aggregate<<<(N + 3) / 4, 256, 0, stream>>>(hbuf, row_off, csr4, bs, xb0, N);
  k_gemm_mfma<<<GB, 256, 0, stream>>>(xb0, Wt + (size_t)HID * HID, hbuf, N);
  k_aggregate<<<(N + 3) / 4, 256, 0, stream>>>(hbuf, row_off, csr4, bs + HID, xb1, N);
  k_gemm_mfma<<<GB, 256, 0, stream>>>(xb1, Wt + (size_t)2 * HID * HID, hbuf, N);
  k_aggregate<<<(N + 3) / 4, 256, 0, stream>>>(hbuf, row_off, csr4, bs + 2 * HID, xb0, N);
  k_classifier_mfma<<<GB, 256, 0, stream>>>(xb0, Wch, bc, out, N);
}